// Round 1
// baseline (705.628 us; speedup 1.0000x reference)
//
#include <hip/hip_runtime.h>
#include <hip/hip_cooperative_groups.h>
#include <cmath>

namespace cg = cooperative_groups;

// Temporal Contrast Enhancement — R3: single persistent cooperative kernel.
// Theory: the 7-kernel pipeline's work models at ~60 us (memory roofline:
// 1 cold x read + 3 L3 re-reads + 1 write; VALU ~7 us/pass) but measures
// 235 us with no kernel >53 us -> the gap is the 6 kernel boundaries
// (launch latency + full drain + tail). Fuse everything into one
// cooperative kernel: 735 persistent blocks x 3 tiles, grid.sync() between
// phases. Pass/scan bodies are byte-identical to the verified R2 kernels.

static constexpr int   kT  = 88200;
static constexpr float kSR = 44100.0f;

struct EnvP { float ad, bd, aa, ba, nuamp, reg; };

__device__ __forceinline__ EnvP make_params(const float* tauA, const float* tauD,
                                            const float* nu, const float* dbreg) {
  EnvP p;
  float td = fminf(fmaxf(tauD[0], 1.0f), 100.0f);
  td = fminf(fmaxf(td, 0.1f), 1000.0f) * 0.001f;
  float ta = fminf(fmaxf(tauA[0], 1.0f), 100.0f);
  ta = fminf(fmaxf(ta, 0.1f), 1000.0f) * 0.001f;
  p.ad = expf(-1.0f / (td * kSR));
  p.aa = expf(-1.0f / (ta * kSR));
  p.bd = 1.0f - p.ad;
  p.ba = 1.0f - p.aa;
  p.nuamp = exp10f(fminf(fmaxf(nu[0],    -60.0f),   0.0f) * 0.05f);
  p.reg   = exp10f(fminf(fmaxf(dbreg[0], -120.0f), -60.0f) * 0.05f);
  return p;
}

// MODE: 0=comp_d (A,B of decay env from |x|)
//       1=comp_a (replay yd; A,B of attack env)
//       2=comp_e (replay yd,ya; A,B of decay env on et)
//       3=final  (replay all; out = x * et/(ye+reg))
template <int S, int MODE>
__device__ __forceinline__ void pass_tile(int blk, const float* __restrict__ x,
                                          const EnvP& p,
                                          const float* __restrict__ Yd,
                                          const float* __restrict__ Ya,
                                          const float* __restrict__ Ye,
                                          float* __restrict__ O0,
                                          float* __restrict__ O1,
                                          float* lds) {
  constexpr int PADS = S + 4;                 // padded chunk stride (floats)
  const int t = threadIdx.x;
  const size_t tileBase = (size_t)blk * (256 * S);
  const float4* xg = reinterpret_cast<const float4*>(x + tileBase);

  // ---- stage tile: coalesced global -> padded LDS ----
#pragma unroll
  for (int i = 0; i < S / 4; ++i) {
    int idx = t + i * 256;                    // float4 index within tile
    float4 v = xg[idx];
    int chunk = (idx * 4) / S;
    int off   = idx * 4 - chunk * S;
    *reinterpret_cast<float4*>(&lds[chunk * PADS + off]) = v;
  }
  __syncthreads();

  const int gchunk = blk * 256 + t;
  float* my = &lds[t * PADS];

  if (MODE == 0) {
    float A = -INFINITY, B = 0.0f;
#pragma unroll 2
    for (int i = 0; i < S / 4; ++i) {
      float4 v = *reinterpret_cast<const float4*>(&my[4 * i]);
      float vv[4] = {v.x, v.y, v.z, v.w};
#pragma unroll
      for (int j = 0; j < 4; ++j) {
        float xa = fabsf(vv[j]);
        float bx = p.bd * xa;
        A = fmaxf(xa, fmaf(p.ad, A, bx));
        B = fmaf(p.ad, B, bx);
      }
    }
    O0[gchunk] = A; O1[gchunk] = B;
  } else if (MODE == 1) {
    float yd = Yd[gchunk];
    float A = INFINITY, B = 0.0f;
#pragma unroll 2
    for (int i = 0; i < S / 4; ++i) {
      float4 v = *reinterpret_cast<const float4*>(&my[4 * i]);
      float vv[4] = {v.x, v.y, v.z, v.w};
#pragma unroll
      for (int j = 0; j < 4; ++j) {
        float xa = fabsf(vv[j]);
        yd = fmaxf(xa, fmaf(p.ad, yd, p.bd * xa));
        float by = p.ba * yd;
        A = fminf(yd, fmaf(p.aa, A, by));
        B = fmaf(p.aa, B, by);
      }
    }
    O0[gchunk] = A; O1[gchunk] = B;
  } else if (MODE == 2) {
    float yd = Yd[gchunk], ya = Ya[gchunk];
    float A = -INFINITY, B = 0.0f;
#pragma unroll 2
    for (int i = 0; i < S / 4; ++i) {
      float4 v = *reinterpret_cast<const float4*>(&my[4 * i]);
      float vv[4] = {v.x, v.y, v.z, v.w};
#pragma unroll
      for (int j = 0; j < 4; ++j) {
        float xa = fabsf(vv[j]);
        yd = fmaxf(xa, fmaf(p.ad, yd, p.bd * xa));
        ya = fminf(yd, fmaf(p.aa, ya, p.ba * yd));
        float et = fmaxf((yd - ya) - p.nuamp, 0.0f);
        float bx = p.bd * et;
        A = fmaxf(et, fmaf(p.ad, A, bx));
        B = fmaf(p.ad, B, bx);
      }
    }
    O0[gchunk] = A; O1[gchunk] = B;
  } else {
    float yd = Yd[gchunk], ya = Ya[gchunk], ye = Ye[gchunk];
#pragma unroll 2
    for (int i = 0; i < S / 4; ++i) {
      float4 v = *reinterpret_cast<const float4*>(&my[4 * i]);
      float vv[4] = {v.x, v.y, v.z, v.w};
      float oo[4];
#pragma unroll
      for (int j = 0; j < 4; ++j) {
        float xa = fabsf(vv[j]);
        yd = fmaxf(xa, fmaf(p.ad, yd, p.bd * xa));
        ya = fminf(yd, fmaf(p.aa, ya, p.ba * yd));
        float et = fmaxf((yd - ya) - p.nuamp, 0.0f);
        ye = fmaxf(et, fmaf(p.ad, ye, p.bd * et));
        oo[j] = vv[j] * (et / (ye + p.reg));
      }
      *reinterpret_cast<float4*>(&my[4 * i]) = make_float4(oo[0], oo[1], oo[2], oo[3]);
    }
    __syncthreads();
    float4* og = reinterpret_cast<float4*>(O0 + tileBase);
#pragma unroll
    for (int i = 0; i < S / 4; ++i) {
      int idx = t + i * 256;
      int chunk = (idx * 4) / S;
      int off   = idx * 4 - chunk * S;
      og[idx] = *reinterpret_cast<const float4*>(&lds[chunk * PADS + off]);
    }
  }
  __syncthreads();   // LDS safe to restage (persistent-block tile loop)
}

// ---- Block-parallel scan over one series' chunk summaries -----------------
template <int S, int ATTACK>
__device__ __forceinline__ void scan_series(int s, const float* __restrict__ A,
                                            const float* __restrict__ B,
                                            float* __restrict__ Y, const EnvP& p,
                                            float* sbuf) {
  constexpr int NC  = kT / S;
  constexpr int CPT = (NC + 255) / 256;
  const float alpha = ATTACK ? p.aa : p.ad;
  const float ID_A  = ATTACK ? INFINITY : -INFINITY;
  const int t = threadIdx.x;
  long base = (long)s * NC;
  float gS = powf(alpha, (float)S);

  float ca[CPT], cb[CPT];
  float a = ID_A, b = 0.0f, g = 1.0f;
#pragma unroll
  for (int k = 0; k < CPT; ++k) {
    int c = t * CPT + k;
    if (c < NC) { ca[k] = A[base + c]; cb[k] = B[base + c]; }
    else        { ca[k] = ID_A;        cb[k] = 0.0f; }
    float cg = (c < NC) ? gS : 1.0f;
    float na = ATTACK ? fminf(ca[k], fmaf(cg, a, cb[k]))
                      : fmaxf(ca[k], fmaf(cg, a, cb[k]));
    b = fmaf(cg, b, cb[k]);
    g = cg * g;
    a = na;
  }

  float* sA = sbuf; float* sB = sbuf + 256; float* sG = sbuf + 512;
  sA[t] = a; sB[t] = b; sG[t] = g;
  __syncthreads();
#pragma unroll
  for (int d = 1; d < 256; d <<= 1) {
    float pa = 0.0f, pb = 0.0f, pg = 0.0f;
    if (t >= d) { pa = sA[t - d]; pb = sB[t - d]; pg = sG[t - d]; }
    __syncthreads();
    if (t >= d) {
      float na = ATTACK ? fminf(a, fmaf(g, pa, b)) : fmaxf(a, fmaf(g, pa, b));
      b = fmaf(g, pb, b);
      g = g * pg;
      a = na;
      sA[t] = a; sB[t] = b; sG[t] = g;
    }
    __syncthreads();
  }

  float ea, eb;
  if (t == 0) { ea = ID_A; eb = 0.0f; }
  else        { ea = sA[t - 1]; eb = sB[t - 1]; }

#pragma unroll
  for (int k = 0; k < CPT; ++k) {
    int c = t * CPT + k;
    if (c >= NC) break;
    Y[base + c] = ATTACK ? fminf(ea, eb) : fmaxf(ea, eb);   // eval at y0=0
    float na = ATTACK ? fminf(ca[k], fmaf(gS, ea, cb[k]))
                      : fmaxf(ca[k], fmaf(gS, ea, cb[k]));
    eb = fmaf(gS, eb, cb[k]);
    ea = na;
  }
}

// ---- Fused cooperative kernel: 4 pass phases + 3 scan phases --------------
template <int S>
__global__ __launch_bounds__(256, 3)
void k_fused(const float* __restrict__ x,
             const float* tauA, const float* tauD,
             const float* nu, const float* dbreg,
             float* __restrict__ A, float* __restrict__ B,
             float* __restrict__ Yd, float* __restrict__ Ya,
             float* __restrict__ Ye, float* __restrict__ out,
             int nt, int nseries) {
  constexpr int PADS = S + 4;
  __shared__ float lds[256 * PADS];           // 45056 B at S=40 -> 3 blocks/CU
  cg::grid_group grid = cg::this_grid();
  EnvP p = make_params(tauA, tauD, nu, dbreg);

  for (int tb = blockIdx.x; tb < nt; tb += gridDim.x)
    pass_tile<S, 0>(tb, x, p, nullptr, nullptr, nullptr, A, B, lds);
  grid.sync();
  if (blockIdx.x < nseries) scan_series<S, 0>(blockIdx.x, A, B, Yd, p, lds);
  grid.sync();
  for (int tb = blockIdx.x; tb < nt; tb += gridDim.x)
    pass_tile<S, 1>(tb, x, p, Yd, nullptr, nullptr, A, B, lds);
  grid.sync();
  if (blockIdx.x < nseries) scan_series<S, 1>(blockIdx.x, A, B, Ya, p, lds);
  grid.sync();
  for (int tb = blockIdx.x; tb < nt; tb += gridDim.x)
    pass_tile<S, 2>(tb, x, p, Yd, Ya, nullptr, A, B, lds);
  grid.sync();
  if (blockIdx.x < nseries) scan_series<S, 0>(blockIdx.x, A, B, Ye, p, lds);
  grid.sync();
  for (int tb = blockIdx.x; tb < nt; tb += gridDim.x)
    pass_tile<S, 3>(tb, x, p, Yd, Ya, Ye, out, nullptr, lds);
}

// ---- Fallback: the verified 7-kernel pipeline -----------------------------
template <int S, int MODE>
__global__ __launch_bounds__(256)
void k_pass(const float* __restrict__ x, const float* tauA, const float* tauD,
            const float* nu, const float* dbreg,
            const float* __restrict__ Yd, const float* __restrict__ Ya,
            const float* __restrict__ Ye,
            float* __restrict__ O0, float* __restrict__ O1) {
  constexpr int PADS = S + 4;
  __shared__ float lds[256 * PADS];
  EnvP p = make_params(tauA, tauD, nu, dbreg);
  pass_tile<S, MODE>(blockIdx.x, x, p, Yd, Ya, Ye, O0, O1, lds);
}

template <int S, int ATTACK>
__global__ __launch_bounds__(256)
void k_scan(const float* __restrict__ A, const float* __restrict__ B,
            float* __restrict__ Y,
            const float* tauA, const float* tauD,
            const float* nu, const float* dbreg) {
  __shared__ float sbuf[768];
  EnvP p = make_params(tauA, tauD, nu, dbreg);
  scan_series<S, ATTACK>(blockIdx.x, A, B, Y, p, sbuf);
}

template <int S>
static void run_pipeline(const float* x, const float* tauA, const float* tauD,
                         const float* nu, const float* dbreg, float* out,
                         float* wsf, int nseries, hipStream_t stream) {
  const int nc  = kT / S;
  const int nch = nseries * nc;
  float* A  = wsf;
  float* B  = wsf + (size_t)nch;
  float* Yd = wsf + (size_t)2 * nch;
  float* Ya = wsf + (size_t)3 * nch;
  float* Ye = wsf + (size_t)4 * nch;
  const int grid = nch / 256;

  k_pass<S, 0><<<grid, 256, 0, stream>>>(x, tauA, tauD, nu, dbreg, nullptr, nullptr, nullptr, A, B);
  k_scan<S, 0><<<nseries, 256, 0, stream>>>(A, B, Yd, tauA, tauD, nu, dbreg);
  k_pass<S, 1><<<grid, 256, 0, stream>>>(x, tauA, tauD, nu, dbreg, Yd, nullptr, nullptr, A, B);
  k_scan<S, 1><<<nseries, 256, 0, stream>>>(A, B, Ya, tauA, tauD, nu, dbreg);
  k_pass<S, 2><<<grid, 256, 0, stream>>>(x, tauA, tauD, nu, dbreg, Yd, Ya, nullptr, A, B);
  k_scan<S, 0><<<nseries, 256, 0, stream>>>(A, B, Ye, tauA, tauD, nu, dbreg);
  k_pass<S, 3><<<grid, 256, 0, stream>>>(x, tauA, tauD, nu, dbreg, Yd, Ya, Ye, out, nullptr);
}

extern "C" void kernel_launch(void* const* d_in, const int* in_sizes, int n_in,
                              void* d_out, int out_size, void* d_ws, size_t ws_size,
                              hipStream_t stream) {
  const float* x     = (const float*)d_in[0];
  const float* tauA  = (const float*)d_in[1];
  const float* tauD  = (const float*)d_in[2];
  const float* nu    = (const float*)d_in[3];
  const float* dbreg = (const float*)d_in[4];
  float* out = (float*)d_out;
  float* wsf = (float*)d_ws;
  const int nseries = in_sizes[0] / kT;       // 256

  constexpr int S  = 40;
  constexpr int NC = kT / S;                  // 2205
  const int nch = nseries * NC;
  const bool shapeOK = (nch % 256) == 0;
  const bool wsOK    = (size_t)5 * nch * sizeof(float) <= ws_size;

  if (shapeOK && wsOK) {
    const int nt = nch / 256;                 // 2205 tiles
    float* A  = wsf;
    float* B  = wsf + (size_t)nch;
    float* Yd = wsf + (size_t)2 * nch;
    float* Ya = wsf + (size_t)3 * nch;
    float* Ye = wsf + (size_t)4 * nch;

    // One-time capability probe (host-side queries only; capture-safe).
    static int cap = -2;
    if (cap == -2) {
      int dev = 0; hipGetDevice(&dev);
      int coop = 0;
      hipDeviceGetAttribute(&coop, hipDeviceAttributeCooperativeLaunch, dev);
      int nblk = 0, ncu = 0;
      hipError_t e1 = hipOccupancyMaxActiveBlocksPerMultiprocessor(
          &nblk, reinterpret_cast<const void*>(&k_fused<S>), 256, 0);
      hipDeviceGetAttribute(&ncu, hipDeviceAttributeMultiprocessorCount, dev);
      cap = (coop && e1 == hipSuccess && nblk > 0 && ncu > 0) ? nblk * ncu : -1;
    }

    if (cap >= nseries) {
      int grid = cap < nt ? cap : nt;
      // Balance: equal tiles per block (cap>=735 -> grid=735, 3 tiles each),
      // but never drop below nseries (scan phases need one block per series).
      int tpb = (nt + grid - 1) / grid;
      int g2  = (nt + tpb - 1) / tpb;
      if (g2 >= nseries) grid = g2;

      const float* xl = x;
      const float* ta = tauA; const float* td = tauD;
      const float* nl = nu;   const float* dl = dbreg;
      float* Al = A; float* Bl = B; float* Ydl = Yd; float* Yal = Ya; float* Yel = Ye;
      float* ol = out;
      int ntl = nt, nsl = nseries;
      void* args[] = {(void*)&xl, (void*)&ta, (void*)&td, (void*)&nl, (void*)&dl,
                      (void*)&Al, (void*)&Bl, (void*)&Ydl, (void*)&Yal, (void*)&Yel,
                      (void*)&ol, (void*)&ntl, (void*)&nsl};
      hipError_t e = hipLaunchCooperativeKernel(
          reinterpret_cast<const void*>(&k_fused<S>), dim3(grid), dim3(256),
          args, 0, stream);
      if (e == hipSuccess) return;
    }
    run_pipeline<S>(x, tauA, tauD, nu, dbreg, out, wsf, nseries, stream);
    return;
  }

  // Tiny-workspace fallback: S=120 (ws = 5*nseries*735*4 B).
  run_pipeline<120>(x, tauA, tauD, nu, dbreg, out, wsf, nseries, stream);
}

// Round 2
// 295.905 us; speedup vs baseline: 2.3846x; 2.3846x over previous
//
#include <hip/hip_runtime.h>
#include <cmath>

// Temporal Contrast Enhancement — R4: one-block-per-series full fusion.
// R1 post-mortem: cooperative grid.sync() costs ~90us each on 8 XCDs
// (VALUBusy 6%, HBM 6.6% during 590us) -> grid-wide sync is WORSE than a
// kernel boundary. But the scan dependency is per-series only: with one
// 256-thread block per series (256 blocks = 256 CUs), the 2205 chunk
// summaries (17.6KB) fit in LDS, the chunk-scan becomes an in-block scan,
// and all 4 passes + 3 scans fuse into ONE ordinary kernel with
// __syncthreads() as the only barrier. Intermediates never touch global.
// x streamed 4x via double-buffered LDS tiles with async reg-staging
// (issue next-tile loads -> compute current -> ds_write).

static constexpr int   kT  = 88200;
static constexpr float kSR = 44100.0f;

static constexpr int S       = 40;                  // chunk length
static constexpr int NC      = kT / S;              // 2205 chunks/series
static constexpr int PADS    = S + 4;               // padded LDS chunk stride
static constexpr int CHT     = 256;                 // chunks per tile (=threads)
static constexpr int NT      = (NC + CHT - 1) / CHT;    // 9 tiles
static constexpr int TAILC   = NC - CHT * (NT - 1);     // 157 chunks in tail
static constexpr int F4C     = S / 4;               // 10 float4 per chunk
static constexpr int TILE_F4 = CHT * F4C;           // 2560 float4 per full tile
static constexpr int TAIL_F4 = TAILC * F4C;         // 1570
static constexpr int BUF_F   = CHT * PADS;          // 11264 floats per buffer

struct EnvP { float ad, bd, aa, ba, nuamp, reg; };

__device__ __forceinline__ EnvP make_params(const float* tauA, const float* tauD,
                                            const float* nu, const float* dbreg) {
  EnvP p;
  float td = fminf(fmaxf(tauD[0], 1.0f), 100.0f);
  td = fminf(fmaxf(td, 0.1f), 1000.0f) * 0.001f;
  float ta = fminf(fmaxf(tauA[0], 1.0f), 100.0f);
  ta = fminf(fmaxf(ta, 0.1f), 1000.0f) * 0.001f;
  p.ad = expf(-1.0f / (td * kSR));
  p.aa = expf(-1.0f / (ta * kSR));
  p.bd = 1.0f - p.ad;
  p.ba = 1.0f - p.aa;
  p.nuamp = exp10f(fminf(fmaxf(nu[0],    -60.0f),   0.0f) * 0.05f);
  p.reg   = exp10f(fminf(fmaxf(dbreg[0], -120.0f), -60.0f) * 0.05f);
  return p;
}

// ---- fused-kernel building blocks -----------------------------------------

__device__ __forceinline__ void ldreg(const float* __restrict__ xs, int tile,
                                      int t, float4* r) {
  const float4* xg = reinterpret_cast<const float4*>(xs) + (size_t)tile * TILE_F4;
  const int nf4 = (tile == NT - 1) ? TAIL_F4 : TILE_F4;
#pragma unroll
  for (int i = 0; i < F4C; ++i) {
    int idx = t + i * 256;
    r[i] = xg[idx < nf4 ? idx : 0];           // clamp keeps address in-bounds
  }
}

__device__ __forceinline__ void wrlds(float* __restrict__ buf, const float4* r,
                                      int t) {
#pragma unroll
  for (int i = 0; i < F4C; ++i) {
    int idx = t + i * 256;
    int chunk = idx / F4C;
    int off   = (idx - chunk * F4C) * 4;
    *reinterpret_cast<float4*>(&buf[chunk * PADS + off]) = r[i];
  }
}

// MODE: 0=comp_d  1=comp_a(replay yd)  2=comp_e(replay yd,ya)  3=final
template <int MODE>
__device__ __forceinline__ void sweep(const float* __restrict__ xs,
                                      float* __restrict__ os,
                                      const EnvP& p,
                                      float* __restrict__ buf0,
                                      float* __restrict__ buf1,
                                      float* __restrict__ Ac, float* __restrict__ Bc,
                                      const float* __restrict__ Ydl,
                                      const float* __restrict__ Yal,
                                      const float* __restrict__ Yel,
                                      int t) {
  float4 r[F4C];
  ldreg(xs, 0, t, r);
  wrlds(buf0, r, t);
  __syncthreads();
  int cur = 0;
  for (int it = 0; it < NT; ++it) {
    const bool pf = (it + 1 < NT);
    if (pf) ldreg(xs, it + 1, t, r);          // async: no use until wrlds
    float* bc = cur ? buf1 : buf0;
    float* bn = cur ? buf0 : buf1;
    const int c = it * CHT + t;
    if (c < NC) {
      float* my = &bc[t * PADS];
      if (MODE == 0) {
        float A = -INFINITY, B = 0.0f;
#pragma unroll 2
        for (int i = 0; i < F4C; ++i) {
          float4 v = *reinterpret_cast<const float4*>(&my[4 * i]);
          float vv[4] = {v.x, v.y, v.z, v.w};
#pragma unroll
          for (int j = 0; j < 4; ++j) {
            float xa = fabsf(vv[j]);
            float bx = p.bd * xa;
            A = fmaxf(xa, fmaf(p.ad, A, bx));
            B = fmaf(p.ad, B, bx);
          }
        }
        Ac[c] = A; Bc[c] = B;
      } else if (MODE == 1) {
        float yd = Ydl[c];
        float A = INFINITY, B = 0.0f;
#pragma unroll 2
        for (int i = 0; i < F4C; ++i) {
          float4 v = *reinterpret_cast<const float4*>(&my[4 * i]);
          float vv[4] = {v.x, v.y, v.z, v.w};
#pragma unroll
          for (int j = 0; j < 4; ++j) {
            float xa = fabsf(vv[j]);
            yd = fmaxf(xa, fmaf(p.ad, yd, p.bd * xa));
            float by = p.ba * yd;
            A = fminf(yd, fmaf(p.aa, A, by));
            B = fmaf(p.aa, B, by);
          }
        }
        Ac[c] = A; Bc[c] = B;
      } else if (MODE == 2) {
        float yd = Ydl[c], ya = Yal[c];
        float A = -INFINITY, B = 0.0f;
#pragma unroll 2
        for (int i = 0; i < F4C; ++i) {
          float4 v = *reinterpret_cast<const float4*>(&my[4 * i]);
          float vv[4] = {v.x, v.y, v.z, v.w};
#pragma unroll
          for (int j = 0; j < 4; ++j) {
            float xa = fabsf(vv[j]);
            yd = fmaxf(xa, fmaf(p.ad, yd, p.bd * xa));
            ya = fminf(yd, fmaf(p.aa, ya, p.ba * yd));
            float et = fmaxf((yd - ya) - p.nuamp, 0.0f);
            float bx = p.bd * et;
            A = fmaxf(et, fmaf(p.ad, A, bx));
            B = fmaf(p.ad, B, bx);
          }
        }
        Ac[c] = A; Bc[c] = B;
      } else {
        float yd = Ydl[c], ya = Yal[c], ye = Yel[c];
#pragma unroll 2
        for (int i = 0; i < F4C; ++i) {
          float4 v = *reinterpret_cast<const float4*>(&my[4 * i]);
          float vv[4] = {v.x, v.y, v.z, v.w};
          float oo[4];
#pragma unroll
          for (int j = 0; j < 4; ++j) {
            float xa = fabsf(vv[j]);
            yd = fmaxf(xa, fmaf(p.ad, yd, p.bd * xa));
            ya = fminf(yd, fmaf(p.aa, ya, p.ba * yd));
            float et = fmaxf((yd - ya) - p.nuamp, 0.0f);
            ye = fmaxf(et, fmaf(p.ad, ye, p.bd * et));
            oo[j] = vv[j] * (et / (ye + p.reg));
          }
          *reinterpret_cast<float4*>(&my[4 * i]) =
              make_float4(oo[0], oo[1], oo[2], oo[3]);
        }
      }
    }
    if (MODE == 3) {
      __syncthreads();                        // results in bc visible to all
      float4* og = reinterpret_cast<float4*>(os) + (size_t)it * TILE_F4;
      const int nf4 = pf ? TILE_F4 : TAIL_F4;
#pragma unroll
      for (int i = 0; i < F4C; ++i) {
        int idx = t + i * 256;
        if (idx < nf4) {
          int chunk = idx / F4C;
          int off   = (idx - chunk * F4C) * 4;
          og[idx] = *reinterpret_cast<const float4*>(&bc[chunk * PADS + off]);
        }
      }
    }
    if (pf) wrlds(bn, r, t);                  // vmcnt waits land here
    __syncthreads();
    cur ^= 1;
  }
}

// In-block exclusive scan over this series' NC chunk summaries (LDS-resident).
template <int ATTACK>
__device__ __forceinline__ void scan_lds(const float* __restrict__ Ac,
                                         const float* __restrict__ Bc,
                                         float* __restrict__ Y,
                                         const EnvP& p,
                                         float* __restrict__ sbuf, int t) {
  constexpr int CPT = (NC + 255) / 256;       // 9
  const float alpha = ATTACK ? p.aa : p.ad;
  const float ID_A  = ATTACK ? INFINITY : -INFINITY;
  const float gS = powf(alpha, (float)S);

  float ca[CPT], cb[CPT];
  float a = ID_A, b = 0.0f, g = 1.0f;
#pragma unroll
  for (int k = 0; k < CPT; ++k) {
    int c = t * CPT + k;
    if (c < NC) { ca[k] = Ac[c]; cb[k] = Bc[c]; }
    else        { ca[k] = ID_A;  cb[k] = 0.0f; }
    float cg = (c < NC) ? gS : 1.0f;
    float na = ATTACK ? fminf(ca[k], fmaf(cg, a, cb[k]))
                      : fmaxf(ca[k], fmaf(cg, a, cb[k]));
    b = fmaf(cg, b, cb[k]);
    g = cg * g;
    a = na;
  }

  float* sA = sbuf; float* sB = sbuf + 256; float* sG = sbuf + 512;
  sA[t] = a; sB[t] = b; sG[t] = g;
  __syncthreads();
#pragma unroll
  for (int d = 1; d < 256; d <<= 1) {
    float pa = 0.0f, pb = 0.0f, pg = 0.0f;
    if (t >= d) { pa = sA[t - d]; pb = sB[t - d]; pg = sG[t - d]; }
    __syncthreads();
    if (t >= d) {
      float na = ATTACK ? fminf(a, fmaf(g, pa, b)) : fmaxf(a, fmaf(g, pa, b));
      b = fmaf(g, pb, b);
      g = g * pg;
      a = na;
      sA[t] = a; sB[t] = b; sG[t] = g;
    }
    __syncthreads();
  }

  float ea, eb;
  if (t == 0) { ea = ID_A; eb = 0.0f; }
  else        { ea = sA[t - 1]; eb = sB[t - 1]; }

#pragma unroll
  for (int k = 0; k < CPT; ++k) {
    int c = t * CPT + k;
    if (c >= NC) break;
    Y[c] = ATTACK ? fminf(ea, eb) : fmaxf(ea, eb);   // eval at y0=0
    float na = ATTACK ? fminf(ca[k], fmaf(gS, ea, cb[k]))
                      : fmaxf(ca[k], fmaf(gS, ea, cb[k]));
    eb = fmaf(gS, eb, cb[k]);
    ea = na;
  }
}

// ---- the fused one-block-per-series kernel --------------------------------
__global__ __launch_bounds__(256)
void k_one(const float* __restrict__ x,
           const float* tauA, const float* tauD,
           const float* nu, const float* dbreg,
           float* __restrict__ out) {
  extern __shared__ float lds[];
  float* buf0 = lds;                          // 11264 f
  float* buf1 = lds + BUF_F;                  // 11264 f
  float* Ac   = lds + 2 * BUF_F;              // 2205 f
  float* Bc   = Ac + NC;                      // 2205 f
  float* Yd   = Bc + NC;                      // 2205 f
  float* Ya   = Yd + NC;                      // 2205 f
  float* Ye   = Ya + NC;                      // 2205 f  -> total 134212 B
  const int t = threadIdx.x;
  const float* xs = x   + (size_t)blockIdx.x * kT;
  float*       os = out + (size_t)blockIdx.x * kT;
  EnvP p = make_params(tauA, tauD, nu, dbreg);

  sweep<0>(xs, nullptr, p, buf0, buf1, Ac, Bc, nullptr, nullptr, nullptr, t);
  scan_lds<0>(Ac, Bc, Yd, p, buf0, t);        // buf0 free between sweeps
  __syncthreads();
  sweep<1>(xs, nullptr, p, buf0, buf1, Ac, Bc, Yd, nullptr, nullptr, t);
  scan_lds<1>(Ac, Bc, Ya, p, buf0, t);
  __syncthreads();
  sweep<2>(xs, nullptr, p, buf0, buf1, Ac, Bc, Yd, Ya, nullptr, t);
  scan_lds<0>(Ac, Bc, Ye, p, buf0, t);
  __syncthreads();
  sweep<3>(xs, os, p, buf0, buf1, Ac, Bc, Yd, Ya, Ye, t);
}

// ---- Fallback: the verified 235us 7-kernel pipeline -----------------------
template <int FS, int MODE>
__global__ __launch_bounds__(256)
void k_pass(const float* __restrict__ x,
            const float* tauA, const float* tauD,
            const float* nu, const float* dbreg,
            const float* __restrict__ FYd, const float* __restrict__ FYa,
            const float* __restrict__ FYe,
            float* __restrict__ O0, float* __restrict__ O1) {
  constexpr int FP = FS + 4;
  __shared__ float lds[256 * FP];
  const int t   = threadIdx.x;
  const int blk = blockIdx.x;
  const size_t tileBase = (size_t)blk * (256 * FS);
  const float4* xg = reinterpret_cast<const float4*>(x + tileBase);
#pragma unroll
  for (int i = 0; i < FS / 4; ++i) {
    int idx = t + i * 256;
    float4 v = xg[idx];
    int chunk = (idx * 4) / FS;
    int off   = idx * 4 - chunk * FS;
    *reinterpret_cast<float4*>(&lds[chunk * FP + off]) = v;
  }
  __syncthreads();
  EnvP p = make_params(tauA, tauD, nu, dbreg);
  const int gchunk = blk * 256 + t;
  float* my = &lds[t * FP];
  if (MODE == 0) {
    float A = -INFINITY, B = 0.0f;
#pragma unroll 2
    for (int i = 0; i < FS / 4; ++i) {
      float4 v = *reinterpret_cast<const float4*>(&my[4 * i]);
      float vv[4] = {v.x, v.y, v.z, v.w};
#pragma unroll
      for (int j = 0; j < 4; ++j) {
        float xa = fabsf(vv[j]);
        float bx = p.bd * xa;
        A = fmaxf(xa, fmaf(p.ad, A, bx));
        B = fmaf(p.ad, B, bx);
      }
    }
    O0[gchunk] = A; O1[gchunk] = B;
  } else if (MODE == 1) {
    float yd = FYd[gchunk];
    float A = INFINITY, B = 0.0f;
#pragma unroll 2
    for (int i = 0; i < FS / 4; ++i) {
      float4 v = *reinterpret_cast<const float4*>(&my[4 * i]);
      float vv[4] = {v.x, v.y, v.z, v.w};
#pragma unroll
      for (int j = 0; j < 4; ++j) {
        float xa = fabsf(vv[j]);
        yd = fmaxf(xa, fmaf(p.ad, yd, p.bd * xa));
        float by = p.ba * yd;
        A = fminf(yd, fmaf(p.aa, A, by));
        B = fmaf(p.aa, B, by);
      }
    }
    O0[gchunk] = A; O1[gchunk] = B;
  } else if (MODE == 2) {
    float yd = FYd[gchunk], ya = FYa[gchunk];
    float A = -INFINITY, B = 0.0f;
#pragma unroll 2
    for (int i = 0; i < FS / 4; ++i) {
      float4 v = *reinterpret_cast<const float4*>(&my[4 * i]);
      float vv[4] = {v.x, v.y, v.z, v.w};
#pragma unroll
      for (int j = 0; j < 4; ++j) {
        float xa = fabsf(vv[j]);
        yd = fmaxf(xa, fmaf(p.ad, yd, p.bd * xa));
        ya = fminf(yd, fmaf(p.aa, ya, p.ba * yd));
        float et = fmaxf((yd - ya) - p.nuamp, 0.0f);
        float bx = p.bd * et;
        A = fmaxf(et, fmaf(p.ad, A, bx));
        B = fmaf(p.ad, B, bx);
      }
    }
    O0[gchunk] = A; O1[gchunk] = B;
  } else {
    float yd = FYd[gchunk], ya = FYa[gchunk], ye = FYe[gchunk];
#pragma unroll 2
    for (int i = 0; i < FS / 4; ++i) {
      float4 v = *reinterpret_cast<const float4*>(&my[4 * i]);
      float vv[4] = {v.x, v.y, v.z, v.w};
      float oo[4];
#pragma unroll
      for (int j = 0; j < 4; ++j) {
        float xa = fabsf(vv[j]);
        yd = fmaxf(xa, fmaf(p.ad, yd, p.bd * xa));
        ya = fminf(yd, fmaf(p.aa, ya, p.ba * yd));
        float et = fmaxf((yd - ya) - p.nuamp, 0.0f);
        ye = fmaxf(et, fmaf(p.ad, ye, p.bd * et));
        oo[j] = vv[j] * (et / (ye + p.reg));
      }
      *reinterpret_cast<float4*>(&my[4 * i]) = make_float4(oo[0], oo[1], oo[2], oo[3]);
    }
    __syncthreads();
    float4* og = reinterpret_cast<float4*>(O0 + tileBase);
#pragma unroll
    for (int i = 0; i < FS / 4; ++i) {
      int idx = t + i * 256;
      int chunk = (idx * 4) / FS;
      int off   = idx * 4 - chunk * FS;
      og[idx] = *reinterpret_cast<const float4*>(&lds[chunk * FP + off]);
    }
  }
}

template <int FS, int ATTACK>
__global__ __launch_bounds__(256)
void k_scan(const float* __restrict__ A, const float* __restrict__ B,
            float* __restrict__ Y,
            const float* tauA, const float* tauD,
            const float* nu, const float* dbreg) {
  constexpr int FNC = kT / FS;
  constexpr int CPT = (FNC + 255) / 256;
  EnvP p = make_params(tauA, tauD, nu, dbreg);
  const float alpha = ATTACK ? p.aa : p.ad;
  const float ID_A  = ATTACK ? INFINITY : -INFINITY;
  int s = blockIdx.x, t = threadIdx.x;
  long base = (long)s * FNC;
  float gS = powf(alpha, (float)FS);

  float ca[CPT], cb[CPT];
  float a = ID_A, b = 0.0f, g = 1.0f;
#pragma unroll
  for (int k = 0; k < CPT; ++k) {
    int c = t * CPT + k;
    if (c < FNC) { ca[k] = A[base + c]; cb[k] = B[base + c]; }
    else         { ca[k] = ID_A;        cb[k] = 0.0f; }
    float cg = (c < FNC) ? gS : 1.0f;
    float na = ATTACK ? fminf(ca[k], fmaf(cg, a, cb[k]))
                      : fmaxf(ca[k], fmaf(cg, a, cb[k]));
    b = fmaf(cg, b, cb[k]);
    g = cg * g;
    a = na;
  }

  __shared__ float sA[256], sB[256], sG[256];
  sA[t] = a; sB[t] = b; sG[t] = g;
  __syncthreads();
#pragma unroll
  for (int d = 1; d < 256; d <<= 1) {
    float pa = 0.0f, pb = 0.0f, pg = 0.0f;
    if (t >= d) { pa = sA[t - d]; pb = sB[t - d]; pg = sG[t - d]; }
    __syncthreads();
    if (t >= d) {
      float na = ATTACK ? fminf(a, fmaf(g, pa, b)) : fmaxf(a, fmaf(g, pa, b));
      b = fmaf(g, pb, b);
      g = g * pg;
      a = na;
      sA[t] = a; sB[t] = b; sG[t] = g;
    }
    __syncthreads();
  }

  float ea, eb;
  if (t == 0) { ea = ID_A; eb = 0.0f; }
  else        { ea = sA[t - 1]; eb = sB[t - 1]; }

#pragma unroll
  for (int k = 0; k < CPT; ++k) {
    int c = t * CPT + k;
    if (c >= FNC) break;
    Y[base + c] = ATTACK ? fminf(ea, eb) : fmaxf(ea, eb);
    float na = ATTACK ? fminf(ca[k], fmaf(gS, ea, cb[k]))
                      : fmaxf(ca[k], fmaf(gS, ea, cb[k]));
    eb = fmaf(gS, eb, cb[k]);
    ea = na;
  }
}

template <int FS>
static void run_pipeline(const float* x, const float* tauA, const float* tauD,
                         const float* nu, const float* dbreg, float* out,
                         float* wsf, int nseries, hipStream_t stream) {
  const int nc  = kT / FS;
  const int nch = nseries * nc;
  float* A   = wsf;
  float* B   = wsf + (size_t)nch;
  float* FYd = wsf + (size_t)2 * nch;
  float* FYa = wsf + (size_t)3 * nch;
  float* FYe = wsf + (size_t)4 * nch;
  const int grid = nch / 256;

  k_pass<FS, 0><<<grid, 256, 0, stream>>>(x, tauA, tauD, nu, dbreg, nullptr, nullptr, nullptr, A, B);
  k_scan<FS, 0><<<nseries, 256, 0, stream>>>(A, B, FYd, tauA, tauD, nu, dbreg);
  k_pass<FS, 1><<<grid, 256, 0, stream>>>(x, tauA, tauD, nu, dbreg, FYd, nullptr, nullptr, A, B);
  k_scan<FS, 1><<<nseries, 256, 0, stream>>>(A, B, FYa, tauA, tauD, nu, dbreg);
  k_pass<FS, 2><<<grid, 256, 0, stream>>>(x, tauA, tauD, nu, dbreg, FYd, FYa, nullptr, A, B);
  k_scan<FS, 0><<<nseries, 256, 0, stream>>>(A, B, FYe, tauA, tauD, nu, dbreg);
  k_pass<FS, 3><<<grid, 256, 0, stream>>>(x, tauA, tauD, nu, dbreg, FYd, FYa, FYe, out, nullptr);
}

extern "C" void kernel_launch(void* const* d_in, const int* in_sizes, int n_in,
                              void* d_out, int out_size, void* d_ws, size_t ws_size,
                              hipStream_t stream) {
  const float* x     = (const float*)d_in[0];
  const float* tauA  = (const float*)d_in[1];
  const float* tauD  = (const float*)d_in[2];
  const float* nu    = (const float*)d_in[3];
  const float* dbreg = (const float*)d_in[4];
  float* out = (float*)d_out;
  float* wsf = (float*)d_ws;
  const int nseries = in_sizes[0] / kT;       // 256

  constexpr size_t LDSZ = (size_t)(2 * BUF_F + 5 * NC) * sizeof(float); // 134212 B

  static int fusedOK = -1;                    // one-time host-side probe
  if (fusedOK < 0) {
    hipFuncSetAttribute(reinterpret_cast<const void*>(&k_one),
                        hipFuncAttributeMaxDynamicSharedMemorySize, (int)LDSZ);
    (void)hipGetLastError();                  // clear any error state
    fusedOK = 1;
  }

  if (fusedOK == 1) {
    k_one<<<nseries, 256, LDSZ, stream>>>(x, tauA, tauD, nu, dbreg, out);
    if (hipGetLastError() == hipSuccess) return;
    fusedOK = 0;                              // LDS rejected -> pipeline forever
  }

  auto fits = [&](int FS) {
    return (size_t)5 * nseries * (kT / FS) * sizeof(float) <= ws_size;
  };
  if      (fits(40))  run_pipeline<40 >(x, tauA, tauD, nu, dbreg, out, wsf, nseries, stream);
  else if (fits(56))  run_pipeline<56 >(x, tauA, tauD, nu, dbreg, out, wsf, nseries, stream);
  else if (fits(72))  run_pipeline<72 >(x, tauA, tauD, nu, dbreg, out, wsf, nseries, stream);
  else                run_pipeline<120>(x, tauA, tauD, nu, dbreg, out, wsf, nseries, stream);
}

// Round 3
// 295.369 us; speedup vs baseline: 2.3890x; 1.0018x over previous
//
#include <hip/hip_runtime.h>
#include <cmath>

// Temporal Contrast Enhancement — R5: one-block-per-series fusion, spill fix.
// R2 post-mortem: k_one compiled at VGPR_Count=64 — with dynamic LDS the
// compiler can't see the 134KB occupancy cap, targeted 8 waves/SIMD, and
// spilled the float4 r[10] staging array to scratch. Counters: WRITE_SIZE
// 307MB vs 90MB ideal (scratch writeback), hbm_bytes 503MB at 2.7TB/s ->
// the kernel was BW-bound on spill traffic. Fix: __launch_bounds__(256,1)
// (LDS already forces 1 block/CU, so a ~160-VGPR allocation is free).

static constexpr int   kT  = 88200;
static constexpr float kSR = 44100.0f;

static constexpr int S       = 40;                  // chunk length
static constexpr int NC      = kT / S;              // 2205 chunks/series
static constexpr int PADS    = S + 4;               // padded LDS chunk stride
static constexpr int CHT     = 256;                 // chunks per tile (=threads)
static constexpr int NT      = (NC + CHT - 1) / CHT;    // 9 tiles
static constexpr int TAILC   = NC - CHT * (NT - 1);     // 157 chunks in tail
static constexpr int F4C     = S / 4;               // 10 float4 per chunk
static constexpr int TILE_F4 = CHT * F4C;           // 2560 float4 per full tile
static constexpr int TAIL_F4 = TAILC * F4C;         // 1570
static constexpr int BUF_F   = CHT * PADS;          // 11264 floats per buffer

struct EnvP { float ad, bd, aa, ba, nuamp, reg; };

__device__ __forceinline__ EnvP make_params(const float* tauA, const float* tauD,
                                            const float* nu, const float* dbreg) {
  EnvP p;
  float td = fminf(fmaxf(tauD[0], 1.0f), 100.0f);
  td = fminf(fmaxf(td, 0.1f), 1000.0f) * 0.001f;
  float ta = fminf(fmaxf(tauA[0], 1.0f), 100.0f);
  ta = fminf(fmaxf(ta, 0.1f), 1000.0f) * 0.001f;
  p.ad = expf(-1.0f / (td * kSR));
  p.aa = expf(-1.0f / (ta * kSR));
  p.bd = 1.0f - p.ad;
  p.ba = 1.0f - p.aa;
  p.nuamp = exp10f(fminf(fmaxf(nu[0],    -60.0f),   0.0f) * 0.05f);
  p.reg   = exp10f(fminf(fmaxf(dbreg[0], -120.0f), -60.0f) * 0.05f);
  return p;
}

// ---- fused-kernel building blocks -----------------------------------------

__device__ __forceinline__ void ldreg(const float* __restrict__ xs, int tile,
                                      int t, float4* r) {
  const float4* xg = reinterpret_cast<const float4*>(xs) + (size_t)tile * TILE_F4;
  const int nf4 = (tile == NT - 1) ? TAIL_F4 : TILE_F4;
#pragma unroll
  for (int i = 0; i < F4C; ++i) {
    int idx = t + i * 256;
    r[i] = xg[idx < nf4 ? idx : 0];           // clamp keeps address in-bounds
  }
}

__device__ __forceinline__ void wrlds(float* __restrict__ buf, const float4* r,
                                      int t) {
#pragma unroll
  for (int i = 0; i < F4C; ++i) {
    int idx = t + i * 256;
    int chunk = idx / F4C;
    int off   = (idx - chunk * F4C) * 4;
    *reinterpret_cast<float4*>(&buf[chunk * PADS + off]) = r[i];
  }
}

// MODE: 0=comp_d  1=comp_a(replay yd)  2=comp_e(replay yd,ya)  3=final
template <int MODE>
__device__ __forceinline__ void sweep(const float* __restrict__ xs,
                                      float* __restrict__ os,
                                      const EnvP& p,
                                      float* __restrict__ buf0,
                                      float* __restrict__ buf1,
                                      float* __restrict__ Ac, float* __restrict__ Bc,
                                      const float* __restrict__ Ydl,
                                      const float* __restrict__ Yal,
                                      const float* __restrict__ Yel,
                                      int t) {
  float4 r[F4C];
  ldreg(xs, 0, t, r);
  wrlds(buf0, r, t);
  __syncthreads();
  int cur = 0;
  for (int it = 0; it < NT; ++it) {
    const bool pf = (it + 1 < NT);
    if (pf) ldreg(xs, it + 1, t, r);          // async: no use until wrlds
    float* bc = cur ? buf1 : buf0;
    float* bn = cur ? buf0 : buf1;
    const int c = it * CHT + t;
    if (c < NC) {
      float* my = &bc[t * PADS];
      if (MODE == 0) {
        float A = -INFINITY, B = 0.0f;
#pragma unroll 2
        for (int i = 0; i < F4C; ++i) {
          float4 v = *reinterpret_cast<const float4*>(&my[4 * i]);
          float vv[4] = {v.x, v.y, v.z, v.w};
#pragma unroll
          for (int j = 0; j < 4; ++j) {
            float xa = fabsf(vv[j]);
            float bx = p.bd * xa;
            A = fmaxf(xa, fmaf(p.ad, A, bx));
            B = fmaf(p.ad, B, bx);
          }
        }
        Ac[c] = A; Bc[c] = B;
      } else if (MODE == 1) {
        float yd = Ydl[c];
        float A = INFINITY, B = 0.0f;
#pragma unroll 2
        for (int i = 0; i < F4C; ++i) {
          float4 v = *reinterpret_cast<const float4*>(&my[4 * i]);
          float vv[4] = {v.x, v.y, v.z, v.w};
#pragma unroll
          for (int j = 0; j < 4; ++j) {
            float xa = fabsf(vv[j]);
            yd = fmaxf(xa, fmaf(p.ad, yd, p.bd * xa));
            float by = p.ba * yd;
            A = fminf(yd, fmaf(p.aa, A, by));
            B = fmaf(p.aa, B, by);
          }
        }
        Ac[c] = A; Bc[c] = B;
      } else if (MODE == 2) {
        float yd = Ydl[c], ya = Yal[c];
        float A = -INFINITY, B = 0.0f;
#pragma unroll 2
        for (int i = 0; i < F4C; ++i) {
          float4 v = *reinterpret_cast<const float4*>(&my[4 * i]);
          float vv[4] = {v.x, v.y, v.z, v.w};
#pragma unroll
          for (int j = 0; j < 4; ++j) {
            float xa = fabsf(vv[j]);
            yd = fmaxf(xa, fmaf(p.ad, yd, p.bd * xa));
            ya = fminf(yd, fmaf(p.aa, ya, p.ba * yd));
            float et = fmaxf((yd - ya) - p.nuamp, 0.0f);
            float bx = p.bd * et;
            A = fmaxf(et, fmaf(p.ad, A, bx));
            B = fmaf(p.ad, B, bx);
          }
        }
        Ac[c] = A; Bc[c] = B;
      } else {
        float yd = Ydl[c], ya = Yal[c], ye = Yel[c];
#pragma unroll 2
        for (int i = 0; i < F4C; ++i) {
          float4 v = *reinterpret_cast<const float4*>(&my[4 * i]);
          float vv[4] = {v.x, v.y, v.z, v.w};
          float oo[4];
#pragma unroll
          for (int j = 0; j < 4; ++j) {
            float xa = fabsf(vv[j]);
            yd = fmaxf(xa, fmaf(p.ad, yd, p.bd * xa));
            ya = fminf(yd, fmaf(p.aa, ya, p.ba * yd));
            float et = fmaxf((yd - ya) - p.nuamp, 0.0f);
            ye = fmaxf(et, fmaf(p.ad, ye, p.bd * et));
            oo[j] = vv[j] * (et / (ye + p.reg));
          }
          *reinterpret_cast<float4*>(&my[4 * i]) =
              make_float4(oo[0], oo[1], oo[2], oo[3]);
        }
      }
    }
    if (MODE == 3) {
      __syncthreads();                        // results in bc visible to all
      float4* og = reinterpret_cast<float4*>(os) + (size_t)it * TILE_F4;
      const int nf4 = pf ? TILE_F4 : TAIL_F4;
#pragma unroll
      for (int i = 0; i < F4C; ++i) {
        int idx = t + i * 256;
        if (idx < nf4) {
          int chunk = idx / F4C;
          int off   = (idx - chunk * F4C) * 4;
          og[idx] = *reinterpret_cast<const float4*>(&bc[chunk * PADS + off]);
        }
      }
    }
    if (pf) wrlds(bn, r, t);                  // vmcnt waits land here
    __syncthreads();
    cur ^= 1;
  }
}

// In-block exclusive scan over this series' NC chunk summaries (LDS-resident).
template <int ATTACK>
__device__ __forceinline__ void scan_lds(const float* __restrict__ Ac,
                                         const float* __restrict__ Bc,
                                         float* __restrict__ Y,
                                         const EnvP& p,
                                         float* __restrict__ sbuf, int t) {
  constexpr int CPT = (NC + 255) / 256;       // 9
  const float alpha = ATTACK ? p.aa : p.ad;
  const float ID_A  = ATTACK ? INFINITY : -INFINITY;
  const float gS = powf(alpha, (float)S);

  float ca[CPT], cb[CPT];
  float a = ID_A, b = 0.0f, g = 1.0f;
#pragma unroll
  for (int k = 0; k < CPT; ++k) {
    int c = t * CPT + k;
    if (c < NC) { ca[k] = Ac[c]; cb[k] = Bc[c]; }
    else        { ca[k] = ID_A;  cb[k] = 0.0f; }
    float cg = (c < NC) ? gS : 1.0f;
    float na = ATTACK ? fminf(ca[k], fmaf(cg, a, cb[k]))
                      : fmaxf(ca[k], fmaf(cg, a, cb[k]));
    b = fmaf(cg, b, cb[k]);
    g = cg * g;
    a = na;
  }

  float* sA = sbuf; float* sB = sbuf + 256; float* sG = sbuf + 512;
  sA[t] = a; sB[t] = b; sG[t] = g;
  __syncthreads();
#pragma unroll
  for (int d = 1; d < 256; d <<= 1) {
    float pa = 0.0f, pb = 0.0f, pg = 0.0f;
    if (t >= d) { pa = sA[t - d]; pb = sB[t - d]; pg = sG[t - d]; }
    __syncthreads();
    if (t >= d) {
      float na = ATTACK ? fminf(a, fmaf(g, pa, b)) : fmaxf(a, fmaf(g, pa, b));
      b = fmaf(g, pb, b);
      g = g * pg;
      a = na;
      sA[t] = a; sB[t] = b; sG[t] = g;
    }
    __syncthreads();
  }

  float ea, eb;
  if (t == 0) { ea = ID_A; eb = 0.0f; }
  else        { ea = sA[t - 1]; eb = sB[t - 1]; }

#pragma unroll
  for (int k = 0; k < CPT; ++k) {
    int c = t * CPT + k;
    if (c >= NC) break;
    Y[c] = ATTACK ? fminf(ea, eb) : fmaxf(ea, eb);   // eval at y0=0
    float na = ATTACK ? fminf(ca[k], fmaf(gS, ea, cb[k]))
                      : fmaxf(ca[k], fmaf(gS, ea, cb[k]));
    eb = fmaf(gS, eb, cb[k]);
    ea = na;
  }
}

// ---- the fused one-block-per-series kernel --------------------------------
// LDS (134KB) already caps occupancy at 1 block/CU; min-waves=1 lets the
// allocator keep the float4 r[10] staging array in registers (no scratch).
__global__ __launch_bounds__(256, 1)
void k_one(const float* __restrict__ x,
           const float* tauA, const float* tauD,
           const float* nu, const float* dbreg,
           float* __restrict__ out) {
  extern __shared__ float lds[];
  float* buf0 = lds;                          // 11264 f
  float* buf1 = lds + BUF_F;                  // 11264 f
  float* Ac   = lds + 2 * BUF_F;              // 2205 f
  float* Bc   = Ac + NC;                      // 2205 f
  float* Yd   = Bc + NC;                      // 2205 f
  float* Ya   = Yd + NC;                      // 2205 f
  float* Ye   = Ya + NC;                      // 2205 f  -> total 134212 B
  const int t = threadIdx.x;
  const float* xs = x   + (size_t)blockIdx.x * kT;
  float*       os = out + (size_t)blockIdx.x * kT;
  EnvP p = make_params(tauA, tauD, nu, dbreg);

  sweep<0>(xs, nullptr, p, buf0, buf1, Ac, Bc, nullptr, nullptr, nullptr, t);
  scan_lds<0>(Ac, Bc, Yd, p, buf0, t);        // buf0 free between sweeps
  __syncthreads();
  sweep<1>(xs, nullptr, p, buf0, buf1, Ac, Bc, Yd, nullptr, nullptr, t);
  scan_lds<1>(Ac, Bc, Ya, p, buf0, t);
  __syncthreads();
  sweep<2>(xs, nullptr, p, buf0, buf1, Ac, Bc, Yd, Ya, nullptr, t);
  scan_lds<0>(Ac, Bc, Ye, p, buf0, t);
  __syncthreads();
  sweep<3>(xs, os, p, buf0, buf1, Ac, Bc, Yd, Ya, Ye, t);
}

// ---- Fallback: the verified 235us 7-kernel pipeline -----------------------
template <int FS, int MODE>
__global__ __launch_bounds__(256)
void k_pass(const float* __restrict__ x,
            const float* tauA, const float* tauD,
            const float* nu, const float* dbreg,
            const float* __restrict__ FYd, const float* __restrict__ FYa,
            const float* __restrict__ FYe,
            float* __restrict__ O0, float* __restrict__ O1) {
  constexpr int FP = FS + 4;
  __shared__ float lds[256 * FP];
  const int t   = threadIdx.x;
  const int blk = blockIdx.x;
  const size_t tileBase = (size_t)blk * (256 * FS);
  const float4* xg = reinterpret_cast<const float4*>(x + tileBase);
#pragma unroll
  for (int i = 0; i < FS / 4; ++i) {
    int idx = t + i * 256;
    float4 v = xg[idx];
    int chunk = (idx * 4) / FS;
    int off   = idx * 4 - chunk * FS;
    *reinterpret_cast<float4*>(&lds[chunk * FP + off]) = v;
  }
  __syncthreads();
  EnvP p = make_params(tauA, tauD, nu, dbreg);
  const int gchunk = blk * 256 + t;
  float* my = &lds[t * FP];
  if (MODE == 0) {
    float A = -INFINITY, B = 0.0f;
#pragma unroll 2
    for (int i = 0; i < FS / 4; ++i) {
      float4 v = *reinterpret_cast<const float4*>(&my[4 * i]);
      float vv[4] = {v.x, v.y, v.z, v.w};
#pragma unroll
      for (int j = 0; j < 4; ++j) {
        float xa = fabsf(vv[j]);
        float bx = p.bd * xa;
        A = fmaxf(xa, fmaf(p.ad, A, bx));
        B = fmaf(p.ad, B, bx);
      }
    }
    O0[gchunk] = A; O1[gchunk] = B;
  } else if (MODE == 1) {
    float yd = FYd[gchunk];
    float A = INFINITY, B = 0.0f;
#pragma unroll 2
    for (int i = 0; i < FS / 4; ++i) {
      float4 v = *reinterpret_cast<const float4*>(&my[4 * i]);
      float vv[4] = {v.x, v.y, v.z, v.w};
#pragma unroll
      for (int j = 0; j < 4; ++j) {
        float xa = fabsf(vv[j]);
        yd = fmaxf(xa, fmaf(p.ad, yd, p.bd * xa));
        float by = p.ba * yd;
        A = fminf(yd, fmaf(p.aa, A, by));
        B = fmaf(p.aa, B, by);
      }
    }
    O0[gchunk] = A; O1[gchunk] = B;
  } else if (MODE == 2) {
    float yd = FYd[gchunk], ya = FYa[gchunk];
    float A = -INFINITY, B = 0.0f;
#pragma unroll 2
    for (int i = 0; i < FS / 4; ++i) {
      float4 v = *reinterpret_cast<const float4*>(&my[4 * i]);
      float vv[4] = {v.x, v.y, v.z, v.w};
#pragma unroll
      for (int j = 0; j < 4; ++j) {
        float xa = fabsf(vv[j]);
        yd = fmaxf(xa, fmaf(p.ad, yd, p.bd * xa));
        ya = fminf(yd, fmaf(p.aa, ya, p.ba * yd));
        float et = fmaxf((yd - ya) - p.nuamp, 0.0f);
        float bx = p.bd * et;
        A = fmaxf(et, fmaf(p.ad, A, bx));
        B = fmaf(p.ad, B, bx);
      }
    }
    O0[gchunk] = A; O1[gchunk] = B;
  } else {
    float yd = FYd[gchunk], ya = FYa[gchunk], ye = FYe[gchunk];
#pragma unroll 2
    for (int i = 0; i < FS / 4; ++i) {
      float4 v = *reinterpret_cast<const float4*>(&my[4 * i]);
      float vv[4] = {v.x, v.y, v.z, v.w};
      float oo[4];
#pragma unroll
      for (int j = 0; j < 4; ++j) {
        float xa = fabsf(vv[j]);
        yd = fmaxf(xa, fmaf(p.ad, yd, p.bd * xa));
        ya = fminf(yd, fmaf(p.aa, ya, p.ba * yd));
        float et = fmaxf((yd - ya) - p.nuamp, 0.0f);
        ye = fmaxf(et, fmaf(p.ad, ye, p.bd * et));
        oo[j] = vv[j] * (et / (ye + p.reg));
      }
      *reinterpret_cast<float4*>(&my[4 * i]) = make_float4(oo[0], oo[1], oo[2], oo[3]);
    }
    __syncthreads();
    float4* og = reinterpret_cast<float4*>(O0 + tileBase);
#pragma unroll
    for (int i = 0; i < FS / 4; ++i) {
      int idx = t + i * 256;
      int chunk = (idx * 4) / FS;
      int off   = idx * 4 - chunk * FS;
      og[idx] = *reinterpret_cast<const float4*>(&lds[chunk * FP + off]);
    }
  }
}

template <int FS, int ATTACK>
__global__ __launch_bounds__(256)
void k_scan(const float* __restrict__ A, const float* __restrict__ B,
            float* __restrict__ Y,
            const float* tauA, const float* tauD,
            const float* nu, const float* dbreg) {
  constexpr int FNC = kT / FS;
  constexpr int CPT = (FNC + 255) / 256;
  EnvP p = make_params(tauA, tauD, nu, dbreg);
  const float alpha = ATTACK ? p.aa : p.ad;
  const float ID_A  = ATTACK ? INFINITY : -INFINITY;
  int s = blockIdx.x, t = threadIdx.x;
  long base = (long)s * FNC;
  float gS = powf(alpha, (float)FS);

  float ca[CPT], cb[CPT];
  float a = ID_A, b = 0.0f, g = 1.0f;
#pragma unroll
  for (int k = 0; k < CPT; ++k) {
    int c = t * CPT + k;
    if (c < FNC) { ca[k] = A[base + c]; cb[k] = B[base + c]; }
    else         { ca[k] = ID_A;        cb[k] = 0.0f; }
    float cg = (c < FNC) ? gS : 1.0f;
    float na = ATTACK ? fminf(ca[k], fmaf(cg, a, cb[k]))
                      : fmaxf(ca[k], fmaf(cg, a, cb[k]));
    b = fmaf(cg, b, cb[k]);
    g = cg * g;
    a = na;
  }

  __shared__ float sA[256], sB[256], sG[256];
  sA[t] = a; sB[t] = b; sG[t] = g;
  __syncthreads();
#pragma unroll
  for (int d = 1; d < 256; d <<= 1) {
    float pa = 0.0f, pb = 0.0f, pg = 0.0f;
    if (t >= d) { pa = sA[t - d]; pb = sB[t - d]; pg = sG[t - d]; }
    __syncthreads();
    if (t >= d) {
      float na = ATTACK ? fminf(a, fmaf(g, pa, b)) : fmaxf(a, fmaf(g, pa, b));
      b = fmaf(g, pb, b);
      g = g * pg;
      a = na;
      sA[t] = a; sB[t] = b; sG[t] = g;
    }
    __syncthreads();
  }

  float ea, eb;
  if (t == 0) { ea = ID_A; eb = 0.0f; }
  else        { ea = sA[t - 1]; eb = sB[t - 1]; }

#pragma unroll
  for (int k = 0; k < CPT; ++k) {
    int c = t * CPT + k;
    if (c >= FNC) break;
    Y[base + c] = ATTACK ? fminf(ea, eb) : fmaxf(ea, eb);
    float na = ATTACK ? fminf(ca[k], fmaf(gS, ea, cb[k]))
                      : fmaxf(ca[k], fmaf(gS, ea, cb[k]));
    eb = fmaf(gS, eb, cb[k]);
    ea = na;
  }
}

template <int FS>
static void run_pipeline(const float* x, const float* tauA, const float* tauD,
                         const float* nu, const float* dbreg, float* out,
                         float* wsf, int nseries, hipStream_t stream) {
  const int nc  = kT / FS;
  const int nch = nseries * nc;
  float* A   = wsf;
  float* B   = wsf + (size_t)nch;
  float* FYd = wsf + (size_t)2 * nch;
  float* FYa = wsf + (size_t)3 * nch;
  float* FYe = wsf + (size_t)4 * nch;
  const int grid = nch / 256;

  k_pass<FS, 0><<<grid, 256, 0, stream>>>(x, tauA, tauD, nu, dbreg, nullptr, nullptr, nullptr, A, B);
  k_scan<FS, 0><<<nseries, 256, 0, stream>>>(A, B, FYd, tauA, tauD, nu, dbreg);
  k_pass<FS, 1><<<grid, 256, 0, stream>>>(x, tauA, tauD, nu, dbreg, FYd, nullptr, nullptr, A, B);
  k_scan<FS, 1><<<nseries, 256, 0, stream>>>(A, B, FYa, tauA, tauD, nu, dbreg);
  k_pass<FS, 2><<<grid, 256, 0, stream>>>(x, tauA, tauD, nu, dbreg, FYd, FYa, nullptr, A, B);
  k_scan<FS, 0><<<nseries, 256, 0, stream>>>(A, B, FYe, tauA, tauD, nu, dbreg);
  k_pass<FS, 3><<<grid, 256, 0, stream>>>(x, tauA, tauD, nu, dbreg, FYd, FYa, FYe, out, nullptr);
}

extern "C" void kernel_launch(void* const* d_in, const int* in_sizes, int n_in,
                              void* d_out, int out_size, void* d_ws, size_t ws_size,
                              hipStream_t stream) {
  const float* x     = (const float*)d_in[0];
  const float* tauA  = (const float*)d_in[1];
  const float* tauD  = (const float*)d_in[2];
  const float* nu    = (const float*)d_in[3];
  const float* dbreg = (const float*)d_in[4];
  float* out = (float*)d_out;
  float* wsf = (float*)d_ws;
  const int nseries = in_sizes[0] / kT;       // 256

  constexpr size_t LDSZ = (size_t)(2 * BUF_F + 5 * NC) * sizeof(float); // 134212 B

  static int fusedOK = -1;                    // one-time host-side probe
  if (fusedOK < 0) {
    hipFuncSetAttribute(reinterpret_cast<const void*>(&k_one),
                        hipFuncAttributeMaxDynamicSharedMemorySize, (int)LDSZ);
    (void)hipGetLastError();                  // clear any error state
    fusedOK = 1;
  }

  if (fusedOK == 1) {
    k_one<<<nseries, 256, LDSZ, stream>>>(x, tauA, tauD, nu, dbreg, out);
    if (hipGetLastError() == hipSuccess) return;
    fusedOK = 0;                              // LDS rejected -> pipeline forever
  }

  auto fits = [&](int FS) {
    return (size_t)5 * nseries * (kT / FS) * sizeof(float) <= ws_size;
  };
  if      (fits(40))  run_pipeline<40 >(x, tauA, tauD, nu, dbreg, out, wsf, nseries, stream);
  else if (fits(56))  run_pipeline<56 >(x, tauA, tauD, nu, dbreg, out, wsf, nseries, stream);
  else if (fits(72))  run_pipeline<72 >(x, tauA, tauD, nu, dbreg, out, wsf, nseries, stream);
  else                run_pipeline<120>(x, tauA, tauD, nu, dbreg, out, wsf, nseries, stream);
}

// Round 4
// 282.857 us; speedup vs baseline: 2.4946x; 1.0442x over previous
//
#include <hip/hip_runtime.h>
#include <cmath>

// Temporal Contrast Enhancement — R6: one-block-per-series fusion, forced
// VGPR budget. R3 post-mortem: __launch_bounds__(256,1) only sets the MIN
// waves/EU — the allocator still targeted 8 waves/SIMD (dynamic LDS is
// invisible to codegen), kept VGPR_Count=64, and spilled the float4 r[10]
// staging array (40 VGPRs) to scratch: +217MB WRITE / +94MB FETCH vs ideal,
// VALUBusy stuck at 19%. Fix: amdgpu_waves_per_eu(1,1) — truthful (134KB
// LDS forces 1 block/CU = 1 wave/SIMD) and raises the register budget so
// staging + recurrence state stay in VGPRs.

static constexpr int   kT  = 88200;
static constexpr float kSR = 44100.0f;

static constexpr int S       = 40;                  // chunk length
static constexpr int NC      = kT / S;              // 2205 chunks/series
static constexpr int PADS    = S + 4;               // padded LDS chunk stride
static constexpr int CHT     = 256;                 // chunks per tile (=threads)
static constexpr int NT      = (NC + CHT - 1) / CHT;    // 9 tiles
static constexpr int TAILC   = NC - CHT * (NT - 1);     // 157 chunks in tail
static constexpr int F4C     = S / 4;               // 10 float4 per chunk
static constexpr int TILE_F4 = CHT * F4C;           // 2560 float4 per full tile
static constexpr int TAIL_F4 = TAILC * F4C;         // 1570
static constexpr int BUF_F   = CHT * PADS;          // 11264 floats per buffer

struct EnvP { float ad, bd, aa, ba, nuamp, reg; };

__device__ __forceinline__ EnvP make_params(const float* tauA, const float* tauD,
                                            const float* nu, const float* dbreg) {
  EnvP p;
  float td = fminf(fmaxf(tauD[0], 1.0f), 100.0f);
  td = fminf(fmaxf(td, 0.1f), 1000.0f) * 0.001f;
  float ta = fminf(fmaxf(tauA[0], 1.0f), 100.0f);
  ta = fminf(fmaxf(ta, 0.1f), 1000.0f) * 0.001f;
  p.ad = expf(-1.0f / (td * kSR));
  p.aa = expf(-1.0f / (ta * kSR));
  p.bd = 1.0f - p.ad;
  p.ba = 1.0f - p.aa;
  p.nuamp = exp10f(fminf(fmaxf(nu[0],    -60.0f),   0.0f) * 0.05f);
  p.reg   = exp10f(fminf(fmaxf(dbreg[0], -120.0f), -60.0f) * 0.05f);
  return p;
}

// ---- fused-kernel building blocks -----------------------------------------

__device__ __forceinline__ void ldreg(const float* __restrict__ xs, int tile,
                                      int t, float4* r) {
  const float4* xg = reinterpret_cast<const float4*>(xs) + (size_t)tile * TILE_F4;
  const int nf4 = (tile == NT - 1) ? TAIL_F4 : TILE_F4;
#pragma unroll
  for (int i = 0; i < F4C; ++i) {
    int idx = t + i * 256;
    r[i] = xg[idx < nf4 ? idx : 0];           // clamp keeps address in-bounds
  }
}

__device__ __forceinline__ void wrlds(float* __restrict__ buf, const float4* r,
                                      int t) {
#pragma unroll
  for (int i = 0; i < F4C; ++i) {
    int idx = t + i * 256;
    int chunk = idx / F4C;
    int off   = (idx - chunk * F4C) * 4;
    *reinterpret_cast<float4*>(&buf[chunk * PADS + off]) = r[i];
  }
}

// MODE: 0=comp_d  1=comp_a(replay yd)  2=comp_e(replay yd,ya)  3=final
template <int MODE>
__device__ __forceinline__ void sweep(const float* __restrict__ xs,
                                      float* __restrict__ os,
                                      const EnvP& p,
                                      float* __restrict__ buf0,
                                      float* __restrict__ buf1,
                                      float* __restrict__ Ac, float* __restrict__ Bc,
                                      const float* __restrict__ Ydl,
                                      const float* __restrict__ Yal,
                                      const float* __restrict__ Yel,
                                      int t) {
  float4 r[F4C];
  ldreg(xs, 0, t, r);
  wrlds(buf0, r, t);
  __syncthreads();
  int cur = 0;
  for (int it = 0; it < NT; ++it) {
    const bool pf = (it + 1 < NT);
    if (pf) ldreg(xs, it + 1, t, r);          // async: no use until wrlds
    float* bc = cur ? buf1 : buf0;
    float* bn = cur ? buf0 : buf1;
    const int c = it * CHT + t;
    if (c < NC) {
      float* my = &bc[t * PADS];
      if (MODE == 0) {
        float A = -INFINITY, B = 0.0f;
#pragma unroll 2
        for (int i = 0; i < F4C; ++i) {
          float4 v = *reinterpret_cast<const float4*>(&my[4 * i]);
          float vv[4] = {v.x, v.y, v.z, v.w};
#pragma unroll
          for (int j = 0; j < 4; ++j) {
            float xa = fabsf(vv[j]);
            float bx = p.bd * xa;
            A = fmaxf(xa, fmaf(p.ad, A, bx));
            B = fmaf(p.ad, B, bx);
          }
        }
        Ac[c] = A; Bc[c] = B;
      } else if (MODE == 1) {
        float yd = Ydl[c];
        float A = INFINITY, B = 0.0f;
#pragma unroll 2
        for (int i = 0; i < F4C; ++i) {
          float4 v = *reinterpret_cast<const float4*>(&my[4 * i]);
          float vv[4] = {v.x, v.y, v.z, v.w};
#pragma unroll
          for (int j = 0; j < 4; ++j) {
            float xa = fabsf(vv[j]);
            yd = fmaxf(xa, fmaf(p.ad, yd, p.bd * xa));
            float by = p.ba * yd;
            A = fminf(yd, fmaf(p.aa, A, by));
            B = fmaf(p.aa, B, by);
          }
        }
        Ac[c] = A; Bc[c] = B;
      } else if (MODE == 2) {
        float yd = Ydl[c], ya = Yal[c];
        float A = -INFINITY, B = 0.0f;
#pragma unroll 2
        for (int i = 0; i < F4C; ++i) {
          float4 v = *reinterpret_cast<const float4*>(&my[4 * i]);
          float vv[4] = {v.x, v.y, v.z, v.w};
#pragma unroll
          for (int j = 0; j < 4; ++j) {
            float xa = fabsf(vv[j]);
            yd = fmaxf(xa, fmaf(p.ad, yd, p.bd * xa));
            ya = fminf(yd, fmaf(p.aa, ya, p.ba * yd));
            float et = fmaxf((yd - ya) - p.nuamp, 0.0f);
            float bx = p.bd * et;
            A = fmaxf(et, fmaf(p.ad, A, bx));
            B = fmaf(p.ad, B, bx);
          }
        }
        Ac[c] = A; Bc[c] = B;
      } else {
        float yd = Ydl[c], ya = Yal[c], ye = Yel[c];
#pragma unroll 2
        for (int i = 0; i < F4C; ++i) {
          float4 v = *reinterpret_cast<const float4*>(&my[4 * i]);
          float vv[4] = {v.x, v.y, v.z, v.w};
          float oo[4];
#pragma unroll
          for (int j = 0; j < 4; ++j) {
            float xa = fabsf(vv[j]);
            yd = fmaxf(xa, fmaf(p.ad, yd, p.bd * xa));
            ya = fminf(yd, fmaf(p.aa, ya, p.ba * yd));
            float et = fmaxf((yd - ya) - p.nuamp, 0.0f);
            ye = fmaxf(et, fmaf(p.ad, ye, p.bd * et));
            oo[j] = vv[j] * (et / (ye + p.reg));
          }
          *reinterpret_cast<float4*>(&my[4 * i]) =
              make_float4(oo[0], oo[1], oo[2], oo[3]);
        }
      }
    }
    if (MODE == 3) {
      __syncthreads();                        // results in bc visible to all
      float4* og = reinterpret_cast<float4*>(os) + (size_t)it * TILE_F4;
      const int nf4 = pf ? TILE_F4 : TAIL_F4;
#pragma unroll
      for (int i = 0; i < F4C; ++i) {
        int idx = t + i * 256;
        if (idx < nf4) {
          int chunk = idx / F4C;
          int off   = (idx - chunk * F4C) * 4;
          og[idx] = *reinterpret_cast<const float4*>(&bc[chunk * PADS + off]);
        }
      }
    }
    if (pf) wrlds(bn, r, t);                  // vmcnt waits land here
    __syncthreads();
    cur ^= 1;
  }
}

// In-block exclusive scan over this series' NC chunk summaries (LDS-resident).
template <int ATTACK>
__device__ __forceinline__ void scan_lds(const float* __restrict__ Ac,
                                         const float* __restrict__ Bc,
                                         float* __restrict__ Y,
                                         const EnvP& p,
                                         float* __restrict__ sbuf, int t) {
  constexpr int CPT = (NC + 255) / 256;       // 9
  const float alpha = ATTACK ? p.aa : p.ad;
  const float ID_A  = ATTACK ? INFINITY : -INFINITY;
  const float gS = powf(alpha, (float)S);

  float ca[CPT], cb[CPT];
  float a = ID_A, b = 0.0f, g = 1.0f;
#pragma unroll
  for (int k = 0; k < CPT; ++k) {
    int c = t * CPT + k;
    if (c < NC) { ca[k] = Ac[c]; cb[k] = Bc[c]; }
    else        { ca[k] = ID_A;  cb[k] = 0.0f; }
    float cg = (c < NC) ? gS : 1.0f;
    float na = ATTACK ? fminf(ca[k], fmaf(cg, a, cb[k]))
                      : fmaxf(ca[k], fmaf(cg, a, cb[k]));
    b = fmaf(cg, b, cb[k]);
    g = cg * g;
    a = na;
  }

  float* sA = sbuf; float* sB = sbuf + 256; float* sG = sbuf + 512;
  sA[t] = a; sB[t] = b; sG[t] = g;
  __syncthreads();
#pragma unroll
  for (int d = 1; d < 256; d <<= 1) {
    float pa = 0.0f, pb = 0.0f, pg = 0.0f;
    if (t >= d) { pa = sA[t - d]; pb = sB[t - d]; pg = sG[t - d]; }
    __syncthreads();
    if (t >= d) {
      float na = ATTACK ? fminf(a, fmaf(g, pa, b)) : fmaxf(a, fmaf(g, pa, b));
      b = fmaf(g, pb, b);
      g = g * pg;
      a = na;
      sA[t] = a; sB[t] = b; sG[t] = g;
    }
    __syncthreads();
  }

  float ea, eb;
  if (t == 0) { ea = ID_A; eb = 0.0f; }
  else        { ea = sA[t - 1]; eb = sB[t - 1]; }

#pragma unroll
  for (int k = 0; k < CPT; ++k) {
    int c = t * CPT + k;
    if (c >= NC) break;
    Y[c] = ATTACK ? fminf(ea, eb) : fmaxf(ea, eb);   // eval at y0=0
    float na = ATTACK ? fminf(ca[k], fmaf(gS, ea, cb[k]))
                      : fmaxf(ca[k], fmaf(gS, ea, cb[k]));
    eb = fmaf(gS, eb, cb[k]);
    ea = na;
  }
}

// ---- the fused one-block-per-series kernel --------------------------------
// amdgpu_waves_per_eu(1,1): truthful (134KB LDS -> 1 block/CU -> 1 wave/SIMD)
// and forces the allocator to budget the full VGPR file -> no scratch spill
// of the float4 r[10] staging array.
__global__
__attribute__((amdgpu_flat_work_group_size(256, 256), amdgpu_waves_per_eu(1, 1)))
void k_one(const float* __restrict__ x,
           const float* tauA, const float* tauD,
           const float* nu, const float* dbreg,
           float* __restrict__ out) {
  extern __shared__ float lds[];
  float* buf0 = lds;                          // 11264 f
  float* buf1 = lds + BUF_F;                  // 11264 f
  float* Ac   = lds + 2 * BUF_F;              // 2205 f
  float* Bc   = Ac + NC;                      // 2205 f
  float* Yd   = Bc + NC;                      // 2205 f
  float* Ya   = Yd + NC;                      // 2205 f
  float* Ye   = Ya + NC;                      // 2205 f  -> total 134212 B
  const int t = threadIdx.x;
  const float* xs = x   + (size_t)blockIdx.x * kT;
  float*       os = out + (size_t)blockIdx.x * kT;
  EnvP p = make_params(tauA, tauD, nu, dbreg);

  sweep<0>(xs, nullptr, p, buf0, buf1, Ac, Bc, nullptr, nullptr, nullptr, t);
  scan_lds<0>(Ac, Bc, Yd, p, buf0, t);        // buf0 free between sweeps
  __syncthreads();
  sweep<1>(xs, nullptr, p, buf0, buf1, Ac, Bc, Yd, nullptr, nullptr, t);
  scan_lds<1>(Ac, Bc, Ya, p, buf0, t);
  __syncthreads();
  sweep<2>(xs, nullptr, p, buf0, buf1, Ac, Bc, Yd, Ya, nullptr, t);
  scan_lds<0>(Ac, Bc, Ye, p, buf0, t);
  __syncthreads();
  sweep<3>(xs, os, p, buf0, buf1, Ac, Bc, Yd, Ya, Ye, t);
}

// ---- Fallback: the verified 235us 7-kernel pipeline -----------------------
template <int FS, int MODE>
__global__ __launch_bounds__(256)
void k_pass(const float* __restrict__ x,
            const float* tauA, const float* tauD,
            const float* nu, const float* dbreg,
            const float* __restrict__ FYd, const float* __restrict__ FYa,
            const float* __restrict__ FYe,
            float* __restrict__ O0, float* __restrict__ O1) {
  constexpr int FP = FS + 4;
  __shared__ float lds[256 * FP];
  const int t   = threadIdx.x;
  const int blk = blockIdx.x;
  const size_t tileBase = (size_t)blk * (256 * FS);
  const float4* xg = reinterpret_cast<const float4*>(x + tileBase);
#pragma unroll
  for (int i = 0; i < FS / 4; ++i) {
    int idx = t + i * 256;
    float4 v = xg[idx];
    int chunk = (idx * 4) / FS;
    int off   = idx * 4 - chunk * FS;
    *reinterpret_cast<float4*>(&lds[chunk * FP + off]) = v;
  }
  __syncthreads();
  EnvP p = make_params(tauA, tauD, nu, dbreg);
  const int gchunk = blk * 256 + t;
  float* my = &lds[t * FP];
  if (MODE == 0) {
    float A = -INFINITY, B = 0.0f;
#pragma unroll 2
    for (int i = 0; i < FS / 4; ++i) {
      float4 v = *reinterpret_cast<const float4*>(&my[4 * i]);
      float vv[4] = {v.x, v.y, v.z, v.w};
#pragma unroll
      for (int j = 0; j < 4; ++j) {
        float xa = fabsf(vv[j]);
        float bx = p.bd * xa;
        A = fmaxf(xa, fmaf(p.ad, A, bx));
        B = fmaf(p.ad, B, bx);
      }
    }
    O0[gchunk] = A; O1[gchunk] = B;
  } else if (MODE == 1) {
    float yd = FYd[gchunk];
    float A = INFINITY, B = 0.0f;
#pragma unroll 2
    for (int i = 0; i < FS / 4; ++i) {
      float4 v = *reinterpret_cast<const float4*>(&my[4 * i]);
      float vv[4] = {v.x, v.y, v.z, v.w};
#pragma unroll
      for (int j = 0; j < 4; ++j) {
        float xa = fabsf(vv[j]);
        yd = fmaxf(xa, fmaf(p.ad, yd, p.bd * xa));
        float by = p.ba * yd;
        A = fminf(yd, fmaf(p.aa, A, by));
        B = fmaf(p.aa, B, by);
      }
    }
    O0[gchunk] = A; O1[gchunk] = B;
  } else if (MODE == 2) {
    float yd = FYd[gchunk], ya = FYa[gchunk];
    float A = -INFINITY, B = 0.0f;
#pragma unroll 2
    for (int i = 0; i < FS / 4; ++i) {
      float4 v = *reinterpret_cast<const float4*>(&my[4 * i]);
      float vv[4] = {v.x, v.y, v.z, v.w};
#pragma unroll
      for (int j = 0; j < 4; ++j) {
        float xa = fabsf(vv[j]);
        yd = fmaxf(xa, fmaf(p.ad, yd, p.bd * xa));
        ya = fminf(yd, fmaf(p.aa, ya, p.ba * yd));
        float et = fmaxf((yd - ya) - p.nuamp, 0.0f);
        float bx = p.bd * et;
        A = fmaxf(et, fmaf(p.ad, A, bx));
        B = fmaf(p.ad, B, bx);
      }
    }
    O0[gchunk] = A; O1[gchunk] = B;
  } else {
    float yd = FYd[gchunk], ya = FYa[gchunk], ye = FYe[gchunk];
#pragma unroll 2
    for (int i = 0; i < FS / 4; ++i) {
      float4 v = *reinterpret_cast<const float4*>(&my[4 * i]);
      float vv[4] = {v.x, v.y, v.z, v.w};
      float oo[4];
#pragma unroll
      for (int j = 0; j < 4; ++j) {
        float xa = fabsf(vv[j]);
        yd = fmaxf(xa, fmaf(p.ad, yd, p.bd * xa));
        ya = fminf(yd, fmaf(p.aa, ya, p.ba * yd));
        float et = fmaxf((yd - ya) - p.nuamp, 0.0f);
        ye = fmaxf(et, fmaf(p.ad, ye, p.bd * et));
        oo[j] = vv[j] * (et / (ye + p.reg));
      }
      *reinterpret_cast<float4*>(&my[4 * i]) = make_float4(oo[0], oo[1], oo[2], oo[3]);
    }
    __syncthreads();
    float4* og = reinterpret_cast<float4*>(O0 + tileBase);
#pragma unroll
    for (int i = 0; i < FS / 4; ++i) {
      int idx = t + i * 256;
      int chunk = (idx * 4) / FS;
      int off   = idx * 4 - chunk * FS;
      og[idx] = *reinterpret_cast<const float4*>(&lds[chunk * FP + off]);
    }
  }
}

template <int FS, int ATTACK>
__global__ __launch_bounds__(256)
void k_scan(const float* __restrict__ A, const float* __restrict__ B,
            float* __restrict__ Y,
            const float* tauA, const float* tauD,
            const float* nu, const float* dbreg) {
  constexpr int FNC = kT / FS;
  constexpr int CPT = (FNC + 255) / 256;
  EnvP p = make_params(tauA, tauD, nu, dbreg);
  const float alpha = ATTACK ? p.aa : p.ad;
  const float ID_A  = ATTACK ? INFINITY : -INFINITY;
  int s = blockIdx.x, t = threadIdx.x;
  long base = (long)s * FNC;
  float gS = powf(alpha, (float)FS);

  float ca[CPT], cb[CPT];
  float a = ID_A, b = 0.0f, g = 1.0f;
#pragma unroll
  for (int k = 0; k < CPT; ++k) {
    int c = t * CPT + k;
    if (c < FNC) { ca[k] = A[base + c]; cb[k] = B[base + c]; }
    else         { ca[k] = ID_A;        cb[k] = 0.0f; }
    float cg = (c < FNC) ? gS : 1.0f;
    float na = ATTACK ? fminf(ca[k], fmaf(cg, a, cb[k]))
                      : fmaxf(ca[k], fmaf(cg, a, cb[k]));
    b = fmaf(cg, b, cb[k]);
    g = cg * g;
    a = na;
  }

  __shared__ float sA[256], sB[256], sG[256];
  sA[t] = a; sB[t] = b; sG[t] = g;
  __syncthreads();
#pragma unroll
  for (int d = 1; d < 256; d <<= 1) {
    float pa = 0.0f, pb = 0.0f, pg = 0.0f;
    if (t >= d) { pa = sA[t - d]; pb = sB[t - d]; pg = sG[t - d]; }
    __syncthreads();
    if (t >= d) {
      float na = ATTACK ? fminf(a, fmaf(g, pa, b)) : fmaxf(a, fmaf(g, pa, b));
      b = fmaf(g, pb, b);
      g = g * pg;
      a = na;
      sA[t] = a; sB[t] = b; sG[t] = g;
    }
    __syncthreads();
  }

  float ea, eb;
  if (t == 0) { ea = ID_A; eb = 0.0f; }
  else        { ea = sA[t - 1]; eb = sB[t - 1]; }

#pragma unroll
  for (int k = 0; k < CPT; ++k) {
    int c = t * CPT + k;
    if (c >= FNC) break;
    Y[base + c] = ATTACK ? fminf(ea, eb) : fmaxf(ea, eb);
    float na = ATTACK ? fminf(ca[k], fmaf(gS, ea, cb[k]))
                      : fmaxf(ca[k], fmaf(gS, ea, cb[k]));
    eb = fmaf(gS, eb, cb[k]);
    ea = na;
  }
}

template <int FS>
static void run_pipeline(const float* x, const float* tauA, const float* tauD,
                         const float* nu, const float* dbreg, float* out,
                         float* wsf, int nseries, hipStream_t stream) {
  const int nc  = kT / FS;
  const int nch = nseries * nc;
  float* A   = wsf;
  float* B   = wsf + (size_t)nch;
  float* FYd = wsf + (size_t)2 * nch;
  float* FYa = wsf + (size_t)3 * nch;
  float* FYe = wsf + (size_t)4 * nch;
  const int grid = nch / 256;

  k_pass<FS, 0><<<grid, 256, 0, stream>>>(x, tauA, tauD, nu, dbreg, nullptr, nullptr, nullptr, A, B);
  k_scan<FS, 0><<<nseries, 256, 0, stream>>>(A, B, FYd, tauA, tauD, nu, dbreg);
  k_pass<FS, 1><<<grid, 256, 0, stream>>>(x, tauA, tauD, nu, dbreg, FYd, nullptr, nullptr, A, B);
  k_scan<FS, 1><<<nseries, 256, 0, stream>>>(A, B, FYa, tauA, tauD, nu, dbreg);
  k_pass<FS, 2><<<grid, 256, 0, stream>>>(x, tauA, tauD, nu, dbreg, FYd, FYa, nullptr, A, B);
  k_scan<FS, 0><<<nseries, 256, 0, stream>>>(A, B, FYe, tauA, tauD, nu, dbreg);
  k_pass<FS, 3><<<grid, 256, 0, stream>>>(x, tauA, tauD, nu, dbreg, FYd, FYa, FYe, out, nullptr);
}

extern "C" void kernel_launch(void* const* d_in, const int* in_sizes, int n_in,
                              void* d_out, int out_size, void* d_ws, size_t ws_size,
                              hipStream_t stream) {
  const float* x     = (const float*)d_in[0];
  const float* tauA  = (const float*)d_in[1];
  const float* tauD  = (const float*)d_in[2];
  const float* nu    = (const float*)d_in[3];
  const float* dbreg = (const float*)d_in[4];
  float* out = (float*)d_out;
  float* wsf = (float*)d_ws;
  const int nseries = in_sizes[0] / kT;       // 256

  constexpr size_t LDSZ = (size_t)(2 * BUF_F + 5 * NC) * sizeof(float); // 134212 B

  static int fusedOK = -1;                    // one-time host-side probe
  if (fusedOK < 0) {
    hipFuncSetAttribute(reinterpret_cast<const void*>(&k_one),
                        hipFuncAttributeMaxDynamicSharedMemorySize, (int)LDSZ);
    (void)hipGetLastError();                  // clear any error state
    fusedOK = 1;
  }

  if (fusedOK == 1) {
    k_one<<<nseries, 256, LDSZ, stream>>>(x, tauA, tauD, nu, dbreg, out);
    if (hipGetLastError() == hipSuccess) return;
    fusedOK = 0;                              // LDS rejected -> pipeline forever
  }

  auto fits = [&](int FS) {
    return (size_t)5 * nseries * (kT / FS) * sizeof(float) <= ws_size;
  };
  if      (fits(40))  run_pipeline<40 >(x, tauA, tauD, nu, dbreg, out, wsf, nseries, stream);
  else if (fits(56))  run_pipeline<56 >(x, tauA, tauD, nu, dbreg, out, wsf, nseries, stream);
  else if (fits(72))  run_pipeline<72 >(x, tauA, tauD, nu, dbreg, out, wsf, nseries, stream);
  else                run_pipeline<120>(x, tauA, tauD, nu, dbreg, out, wsf, nseries, stream);
}

// Round 5
// 218.963 us; speedup vs baseline: 3.2226x; 1.2918x over previous
//
#include <hip/hip_runtime.h>
#include <cmath>

// Temporal Contrast Enhancement — R7: named-register staging, pinned issue.
// R4 post-mortem: VGPR 64->132 (waves_per_eu worked) but WRITE_SIZE stayed
// ~297MB vs 92 ideal and dur only 184->173us. The float4 r[10] staging
// array is still demoted to scratch (rule: arrays through helpers spill)
// and/or the prefetch loads are sunk to their LDS-write use, so nothing
// overlaps compute at 1 wave/SIMD. Fix: ten NAMED float4 registers (no
// array anywhere), sched_barrier(0) after load-issue so the 10 loads are
// issued before the compute region (vmcnt waits land at wrlds, after
// compute), and nontemporal out-stores so out stops evicting x from L3.

typedef float f32x4 __attribute__((ext_vector_type(4)));

static constexpr int   kT  = 88200;
static constexpr float kSR = 44100.0f;

static constexpr int S       = 40;                  // chunk length
static constexpr int NC      = kT / S;              // 2205 chunks/series
static constexpr int PADS    = S + 4;               // padded LDS chunk stride
static constexpr int CHT     = 256;                 // chunks per tile (=threads)
static constexpr int NT      = (NC + CHT - 1) / CHT;    // 9 tiles
static constexpr int TAILC   = NC - CHT * (NT - 1);     // 157 chunks in tail
static constexpr int F4C     = S / 4;               // 10 float4 per chunk
static constexpr int TILE_F4 = CHT * F4C;           // 2560 float4 per full tile
static constexpr int TAIL_F4 = TAILC * F4C;         // 1570
static constexpr int BUF_F   = CHT * PADS;          // 11264 floats per buffer

struct EnvP { float ad, bd, aa, ba, nuamp, reg; };

__device__ __forceinline__ EnvP make_params(const float* tauA, const float* tauD,
                                            const float* nu, const float* dbreg) {
  EnvP p;
  float td = fminf(fmaxf(tauD[0], 1.0f), 100.0f);
  td = fminf(fmaxf(td, 0.1f), 1000.0f) * 0.001f;
  float ta = fminf(fmaxf(tauA[0], 1.0f), 100.0f);
  ta = fminf(fmaxf(ta, 0.1f), 1000.0f) * 0.001f;
  p.ad = expf(-1.0f / (td * kSR));
  p.aa = expf(-1.0f / (ta * kSR));
  p.bd = 1.0f - p.ad;
  p.ba = 1.0f - p.aa;
  p.nuamp = exp10f(fminf(fmaxf(nu[0],    -60.0f),   0.0f) * 0.05f);
  p.reg   = exp10f(fminf(fmaxf(dbreg[0], -120.0f), -60.0f) * 0.05f);
  return p;
}

// MODE: 0=comp_d  1=comp_a(replay yd)  2=comp_e(replay yd,ya)  3=final
template <int MODE>
__device__ __forceinline__ void sweep(const float* __restrict__ xs,
                                      float* __restrict__ os,
                                      const EnvP& p,
                                      float* __restrict__ buf0,
                                      float* __restrict__ buf1,
                                      float* __restrict__ Ac, float* __restrict__ Bc,
                                      const float* __restrict__ Ydl,
                                      const float* __restrict__ Yal,
                                      const float* __restrict__ Yel,
                                      int t) {
  // Ten NAMED staging registers — never an array, never spillable (rule #20).
  f32x4 r0, r1, r2, r3, r4, r5, r6, r7, r8, r9;
  const f32x4* xg4 = reinterpret_cast<const f32x4*>(xs);

#define LD_TILE(TILE)                                                        \
  do {                                                                       \
    const int nf4_ = ((TILE) == NT - 1) ? TAIL_F4 : TILE_F4;                 \
    const f32x4* xg_ = xg4 + (size_t)(TILE) * TILE_F4;                       \
    int i0_ = t;                                                             \
    r0 = xg_[i0_ < nf4_ ? i0_ : 0];  i0_ += 256;                             \
    r1 = xg_[i0_ < nf4_ ? i0_ : 0];  i0_ += 256;                             \
    r2 = xg_[i0_ < nf4_ ? i0_ : 0];  i0_ += 256;                             \
    r3 = xg_[i0_ < nf4_ ? i0_ : 0];  i0_ += 256;                             \
    r4 = xg_[i0_ < nf4_ ? i0_ : 0];  i0_ += 256;                             \
    r5 = xg_[i0_ < nf4_ ? i0_ : 0];  i0_ += 256;                             \
    r6 = xg_[i0_ < nf4_ ? i0_ : 0];  i0_ += 256;                             \
    r7 = xg_[i0_ < nf4_ ? i0_ : 0];  i0_ += 256;                             \
    r8 = xg_[i0_ < nf4_ ? i0_ : 0];  i0_ += 256;                             \
    r9 = xg_[i0_ < nf4_ ? i0_ : 0];                                          \
  } while (0)

#define WR_TILE(BUF)                                                         \
  do {                                                                       \
    float* b_ = (BUF);                                                       \
    int i0_ = t, ch_, of_;                                                   \
    ch_ = i0_ / F4C; of_ = (i0_ - ch_ * F4C) * 4;                            \
    *reinterpret_cast<f32x4*>(&b_[ch_ * PADS + of_]) = r0;  i0_ += 256;      \
    ch_ = i0_ / F4C; of_ = (i0_ - ch_ * F4C) * 4;                            \
    *reinterpret_cast<f32x4*>(&b_[ch_ * PADS + of_]) = r1;  i0_ += 256;      \
    ch_ = i0_ / F4C; of_ = (i0_ - ch_ * F4C) * 4;                            \
    *reinterpret_cast<f32x4*>(&b_[ch_ * PADS + of_]) = r2;  i0_ += 256;      \
    ch_ = i0_ / F4C; of_ = (i0_ - ch_ * F4C) * 4;                            \
    *reinterpret_cast<f32x4*>(&b_[ch_ * PADS + of_]) = r3;  i0_ += 256;      \
    ch_ = i0_ / F4C; of_ = (i0_ - ch_ * F4C) * 4;                            \
    *reinterpret_cast<f32x4*>(&b_[ch_ * PADS + of_]) = r4;  i0_ += 256;      \
    ch_ = i0_ / F4C; of_ = (i0_ - ch_ * F4C) * 4;                            \
    *reinterpret_cast<f32x4*>(&b_[ch_ * PADS + of_]) = r5;  i0_ += 256;      \
    ch_ = i0_ / F4C; of_ = (i0_ - ch_ * F4C) * 4;                            \
    *reinterpret_cast<f32x4*>(&b_[ch_ * PADS + of_]) = r6;  i0_ += 256;      \
    ch_ = i0_ / F4C; of_ = (i0_ - ch_ * F4C) * 4;                            \
    *reinterpret_cast<f32x4*>(&b_[ch_ * PADS + of_]) = r7;  i0_ += 256;      \
    ch_ = i0_ / F4C; of_ = (i0_ - ch_ * F4C) * 4;                            \
    *reinterpret_cast<f32x4*>(&b_[ch_ * PADS + of_]) = r8;  i0_ += 256;      \
    ch_ = i0_ / F4C; of_ = (i0_ - ch_ * F4C) * 4;                            \
    *reinterpret_cast<f32x4*>(&b_[ch_ * PADS + of_]) = r9;                   \
  } while (0)

  LD_TILE(0);
  WR_TILE(buf0);
  __syncthreads();
  int cur = 0;
  for (int it = 0; it < NT; ++it) {
    const bool pf = (it + 1 < NT);
    if (pf) LD_TILE(it + 1);                  // issue next-tile loads NOW
    __builtin_amdgcn_sched_barrier(0);        // pin issue before compute
    float* bc = cur ? buf1 : buf0;
    float* bn = cur ? buf0 : buf1;
    const int c = it * CHT + t;
    if (c < NC) {
      float* my = &bc[t * PADS];
      if (MODE == 0) {
        float A = -INFINITY, B = 0.0f;
#pragma unroll 2
        for (int i = 0; i < F4C; ++i) {
          f32x4 v = *reinterpret_cast<const f32x4*>(&my[4 * i]);
#pragma unroll
          for (int j = 0; j < 4; ++j) {
            float xa = fabsf(v[j]);
            float bx = p.bd * xa;
            A = fmaxf(xa, fmaf(p.ad, A, bx));
            B = fmaf(p.ad, B, bx);
          }
        }
        Ac[c] = A; Bc[c] = B;
      } else if (MODE == 1) {
        float yd = Ydl[c];
        float A = INFINITY, B = 0.0f;
#pragma unroll 2
        for (int i = 0; i < F4C; ++i) {
          f32x4 v = *reinterpret_cast<const f32x4*>(&my[4 * i]);
#pragma unroll
          for (int j = 0; j < 4; ++j) {
            float xa = fabsf(v[j]);
            yd = fmaxf(xa, fmaf(p.ad, yd, p.bd * xa));
            float by = p.ba * yd;
            A = fminf(yd, fmaf(p.aa, A, by));
            B = fmaf(p.aa, B, by);
          }
        }
        Ac[c] = A; Bc[c] = B;
      } else if (MODE == 2) {
        float yd = Ydl[c], ya = Yal[c];
        float A = -INFINITY, B = 0.0f;
#pragma unroll 2
        for (int i = 0; i < F4C; ++i) {
          f32x4 v = *reinterpret_cast<const f32x4*>(&my[4 * i]);
#pragma unroll
          for (int j = 0; j < 4; ++j) {
            float xa = fabsf(v[j]);
            yd = fmaxf(xa, fmaf(p.ad, yd, p.bd * xa));
            ya = fminf(yd, fmaf(p.aa, ya, p.ba * yd));
            float et = fmaxf((yd - ya) - p.nuamp, 0.0f);
            float bx = p.bd * et;
            A = fmaxf(et, fmaf(p.ad, A, bx));
            B = fmaf(p.ad, B, bx);
          }
        }
        Ac[c] = A; Bc[c] = B;
      } else {
        float yd = Ydl[c], ya = Yal[c], ye = Yel[c];
#pragma unroll 2
        for (int i = 0; i < F4C; ++i) {
          f32x4 v = *reinterpret_cast<const f32x4*>(&my[4 * i]);
          f32x4 oo;
#pragma unroll
          for (int j = 0; j < 4; ++j) {
            float xa = fabsf(v[j]);
            yd = fmaxf(xa, fmaf(p.ad, yd, p.bd * xa));
            ya = fminf(yd, fmaf(p.aa, ya, p.ba * yd));
            float et = fmaxf((yd - ya) - p.nuamp, 0.0f);
            ye = fmaxf(et, fmaf(p.ad, ye, p.bd * et));
            oo[j] = v[j] * (et / (ye + p.reg));
          }
          *reinterpret_cast<f32x4*>(&my[4 * i]) = oo;
        }
      }
    }
    if (MODE == 3) {
      __syncthreads();                        // results in bc visible to all
      f32x4* og = reinterpret_cast<f32x4*>(os) + (size_t)it * TILE_F4;
      const int nf4 = pf ? TILE_F4 : TAIL_F4;
#pragma unroll
      for (int i = 0; i < F4C; ++i) {
        int idx = t + i * 256;
        if (idx < nf4) {
          int chunk = idx / F4C;
          int off   = (idx - chunk * F4C) * 4;
          f32x4 v = *reinterpret_cast<const f32x4*>(&bc[chunk * PADS + off]);
          __builtin_nontemporal_store(v, &og[idx]);   // don't evict x from L3
        }
      }
    }
    if (pf) WR_TILE(bn);                      // vmcnt waits land here
    __syncthreads();
    cur ^= 1;
  }
#undef LD_TILE
#undef WR_TILE
}

// In-block exclusive scan over this series' NC chunk summaries (LDS-resident).
template <int ATTACK>
__device__ __forceinline__ void scan_lds(const float* __restrict__ Ac,
                                         const float* __restrict__ Bc,
                                         float* __restrict__ Y,
                                         const EnvP& p,
                                         float* __restrict__ sbuf, int t) {
  constexpr int CPT = (NC + 255) / 256;       // 9
  const float alpha = ATTACK ? p.aa : p.ad;
  const float ID_A  = ATTACK ? INFINITY : -INFINITY;
  const float gS = powf(alpha, (float)S);

  float ca[CPT], cb[CPT];
  float a = ID_A, b = 0.0f, g = 1.0f;
#pragma unroll
  for (int k = 0; k < CPT; ++k) {
    int c = t * CPT + k;
    if (c < NC) { ca[k] = Ac[c]; cb[k] = Bc[c]; }
    else        { ca[k] = ID_A;  cb[k] = 0.0f; }
    float cg = (c < NC) ? gS : 1.0f;
    float na = ATTACK ? fminf(ca[k], fmaf(cg, a, cb[k]))
                      : fmaxf(ca[k], fmaf(cg, a, cb[k]));
    b = fmaf(cg, b, cb[k]);
    g = cg * g;
    a = na;
  }

  float* sA = sbuf; float* sB = sbuf + 256; float* sG = sbuf + 512;
  sA[t] = a; sB[t] = b; sG[t] = g;
  __syncthreads();
#pragma unroll
  for (int d = 1; d < 256; d <<= 1) {
    float pa = 0.0f, pb = 0.0f, pg = 0.0f;
    if (t >= d) { pa = sA[t - d]; pb = sB[t - d]; pg = sG[t - d]; }
    __syncthreads();
    if (t >= d) {
      float na = ATTACK ? fminf(a, fmaf(g, pa, b)) : fmaxf(a, fmaf(g, pa, b));
      b = fmaf(g, pb, b);
      g = g * pg;
      a = na;
      sA[t] = a; sB[t] = b; sG[t] = g;
    }
    __syncthreads();
  }

  float ea, eb;
  if (t == 0) { ea = ID_A; eb = 0.0f; }
  else        { ea = sA[t - 1]; eb = sB[t - 1]; }

#pragma unroll
  for (int k = 0; k < CPT; ++k) {
    int c = t * CPT + k;
    if (c >= NC) break;
    Y[c] = ATTACK ? fminf(ea, eb) : fmaxf(ea, eb);   // eval at y0=0
    float na = ATTACK ? fminf(ca[k], fmaf(gS, ea, cb[k]))
                      : fmaxf(ca[k], fmaf(gS, ea, cb[k]));
    eb = fmaf(gS, eb, cb[k]);
    ea = na;
  }
}

// ---- the fused one-block-per-series kernel --------------------------------
// waves_per_eu(1,1): truthful (134KB LDS -> 1 block/CU -> 1 wave/SIMD);
// full VGPR budget so the ten named staging registers stay resident.
__global__
__attribute__((amdgpu_flat_work_group_size(256, 256), amdgpu_waves_per_eu(1, 1)))
void k_one(const float* __restrict__ x,
           const float* tauA, const float* tauD,
           const float* nu, const float* dbreg,
           float* __restrict__ out) {
  extern __shared__ float lds[];
  float* buf0 = lds;                          // 11264 f
  float* buf1 = lds + BUF_F;                  // 11264 f
  float* Ac   = lds + 2 * BUF_F;              // 2205 f
  float* Bc   = Ac + NC;                      // 2205 f
  float* Yd   = Bc + NC;                      // 2205 f
  float* Ya   = Yd + NC;                      // 2205 f
  float* Ye   = Ya + NC;                      // 2205 f  -> total 134212 B
  const int t = threadIdx.x;
  const float* xs = x   + (size_t)blockIdx.x * kT;
  float*       os = out + (size_t)blockIdx.x * kT;
  EnvP p = make_params(tauA, tauD, nu, dbreg);

  sweep<0>(xs, nullptr, p, buf0, buf1, Ac, Bc, nullptr, nullptr, nullptr, t);
  scan_lds<0>(Ac, Bc, Yd, p, buf0, t);        // buf0 free between sweeps
  __syncthreads();
  sweep<1>(xs, nullptr, p, buf0, buf1, Ac, Bc, Yd, nullptr, nullptr, t);
  scan_lds<1>(Ac, Bc, Ya, p, buf0, t);
  __syncthreads();
  sweep<2>(xs, nullptr, p, buf0, buf1, Ac, Bc, Yd, Ya, nullptr, t);
  scan_lds<0>(Ac, Bc, Ye, p, buf0, t);
  __syncthreads();
  sweep<3>(xs, os, p, buf0, buf1, Ac, Bc, Yd, Ya, Ye, t);
}

// ---- Fallback: the verified 235us 7-kernel pipeline -----------------------
template <int FS, int MODE>
__global__ __launch_bounds__(256)
void k_pass(const float* __restrict__ x,
            const float* tauA, const float* tauD,
            const float* nu, const float* dbreg,
            const float* __restrict__ FYd, const float* __restrict__ FYa,
            const float* __restrict__ FYe,
            float* __restrict__ O0, float* __restrict__ O1) {
  constexpr int FP = FS + 4;
  __shared__ float lds[256 * FP];
  const int t   = threadIdx.x;
  const int blk = blockIdx.x;
  const size_t tileBase = (size_t)blk * (256 * FS);
  const float4* xg = reinterpret_cast<const float4*>(x + tileBase);
#pragma unroll
  for (int i = 0; i < FS / 4; ++i) {
    int idx = t + i * 256;
    float4 v = xg[idx];
    int chunk = (idx * 4) / FS;
    int off   = idx * 4 - chunk * FS;
    *reinterpret_cast<float4*>(&lds[chunk * FP + off]) = v;
  }
  __syncthreads();
  EnvP p = make_params(tauA, tauD, nu, dbreg);
  const int gchunk = blk * 256 + t;
  float* my = &lds[t * FP];
  if (MODE == 0) {
    float A = -INFINITY, B = 0.0f;
#pragma unroll 2
    for (int i = 0; i < FS / 4; ++i) {
      float4 v = *reinterpret_cast<const float4*>(&my[4 * i]);
      float vv[4] = {v.x, v.y, v.z, v.w};
#pragma unroll
      for (int j = 0; j < 4; ++j) {
        float xa = fabsf(vv[j]);
        float bx = p.bd * xa;
        A = fmaxf(xa, fmaf(p.ad, A, bx));
        B = fmaf(p.ad, B, bx);
      }
    }
    O0[gchunk] = A; O1[gchunk] = B;
  } else if (MODE == 1) {
    float yd = FYd[gchunk];
    float A = INFINITY, B = 0.0f;
#pragma unroll 2
    for (int i = 0; i < FS / 4; ++i) {
      float4 v = *reinterpret_cast<const float4*>(&my[4 * i]);
      float vv[4] = {v.x, v.y, v.z, v.w};
#pragma unroll
      for (int j = 0; j < 4; ++j) {
        float xa = fabsf(vv[j]);
        yd = fmaxf(xa, fmaf(p.ad, yd, p.bd * xa));
        float by = p.ba * yd;
        A = fminf(yd, fmaf(p.aa, A, by));
        B = fmaf(p.aa, B, by);
      }
    }
    O0[gchunk] = A; O1[gchunk] = B;
  } else if (MODE == 2) {
    float yd = FYd[gchunk], ya = FYa[gchunk];
    float A = -INFINITY, B = 0.0f;
#pragma unroll 2
    for (int i = 0; i < FS / 4; ++i) {
      float4 v = *reinterpret_cast<const float4*>(&my[4 * i]);
      float vv[4] = {v.x, v.y, v.z, v.w};
#pragma unroll
      for (int j = 0; j < 4; ++j) {
        float xa = fabsf(vv[j]);
        yd = fmaxf(xa, fmaf(p.ad, yd, p.bd * xa));
        ya = fminf(yd, fmaf(p.aa, ya, p.ba * yd));
        float et = fmaxf((yd - ya) - p.nuamp, 0.0f);
        float bx = p.bd * et;
        A = fmaxf(et, fmaf(p.ad, A, bx));
        B = fmaf(p.ad, B, bx);
      }
    }
    O0[gchunk] = A; O1[gchunk] = B;
  } else {
    float yd = FYd[gchunk], ya = FYa[gchunk], ye = FYe[gchunk];
#pragma unroll 2
    for (int i = 0; i < FS / 4; ++i) {
      float4 v = *reinterpret_cast<const float4*>(&my[4 * i]);
      float vv[4] = {v.x, v.y, v.z, v.w};
      float oo[4];
#pragma unroll
      for (int j = 0; j < 4; ++j) {
        float xa = fabsf(vv[j]);
        yd = fmaxf(xa, fmaf(p.ad, yd, p.bd * xa));
        ya = fminf(yd, fmaf(p.aa, ya, p.ba * yd));
        float et = fmaxf((yd - ya) - p.nuamp, 0.0f);
        ye = fmaxf(et, fmaf(p.ad, ye, p.bd * et));
        oo[j] = vv[j] * (et / (ye + p.reg));
      }
      *reinterpret_cast<float4*>(&my[4 * i]) = make_float4(oo[0], oo[1], oo[2], oo[3]);
    }
    __syncthreads();
    float4* og = reinterpret_cast<float4*>(O0 + tileBase);
#pragma unroll
    for (int i = 0; i < FS / 4; ++i) {
      int idx = t + i * 256;
      int chunk = (idx * 4) / FS;
      int off   = idx * 4 - chunk * FS;
      og[idx] = *reinterpret_cast<const float4*>(&lds[chunk * FP + off]);
    }
  }
}

template <int FS, int ATTACK>
__global__ __launch_bounds__(256)
void k_scan(const float* __restrict__ A, const float* __restrict__ B,
            float* __restrict__ Y,
            const float* tauA, const float* tauD,
            const float* nu, const float* dbreg) {
  constexpr int FNC = kT / FS;
  constexpr int CPT = (FNC + 255) / 256;
  EnvP p = make_params(tauA, tauD, nu, dbreg);
  const float alpha = ATTACK ? p.aa : p.ad;
  const float ID_A  = ATTACK ? INFINITY : -INFINITY;
  int s = blockIdx.x, t = threadIdx.x;
  long base = (long)s * FNC;
  float gS = powf(alpha, (float)FS);

  float ca[CPT], cb[CPT];
  float a = ID_A, b = 0.0f, g = 1.0f;
#pragma unroll
  for (int k = 0; k < CPT; ++k) {
    int c = t * CPT + k;
    if (c < FNC) { ca[k] = A[base + c]; cb[k] = B[base + c]; }
    else         { ca[k] = ID_A;        cb[k] = 0.0f; }
    float cg = (c < FNC) ? gS : 1.0f;
    float na = ATTACK ? fminf(ca[k], fmaf(cg, a, cb[k]))
                      : fmaxf(ca[k], fmaf(cg, a, cb[k]));
    b = fmaf(cg, b, cb[k]);
    g = cg * g;
    a = na;
  }

  __shared__ float sA[256], sB[256], sG[256];
  sA[t] = a; sB[t] = b; sG[t] = g;
  __syncthreads();
#pragma unroll
  for (int d = 1; d < 256; d <<= 1) {
    float pa = 0.0f, pb = 0.0f, pg = 0.0f;
    if (t >= d) { pa = sA[t - d]; pb = sB[t - d]; pg = sG[t - d]; }
    __syncthreads();
    if (t >= d) {
      float na = ATTACK ? fminf(a, fmaf(g, pa, b)) : fmaxf(a, fmaf(g, pa, b));
      b = fmaf(g, pb, b);
      g = g * pg;
      a = na;
      sA[t] = a; sB[t] = b; sG[t] = g;
    }
    __syncthreads();
  }

  float ea, eb;
  if (t == 0) { ea = ID_A; eb = 0.0f; }
  else        { ea = sA[t - 1]; eb = sB[t - 1]; }

#pragma unroll
  for (int k = 0; k < CPT; ++k) {
    int c = t * CPT + k;
    if (c >= FNC) break;
    Y[base + c] = ATTACK ? fminf(ea, eb) : fmaxf(ea, eb);
    float na = ATTACK ? fminf(ca[k], fmaf(gS, ea, cb[k]))
                      : fmaxf(ca[k], fmaf(gS, ea, cb[k]));
    eb = fmaf(gS, eb, cb[k]);
    ea = na;
  }
}

template <int FS>
static void run_pipeline(const float* x, const float* tauA, const float* tauD,
                         const float* nu, const float* dbreg, float* out,
                         float* wsf, int nseries, hipStream_t stream) {
  const int nc  = kT / FS;
  const int nch = nseries * nc;
  float* A   = wsf;
  float* B   = wsf + (size_t)nch;
  float* FYd = wsf + (size_t)2 * nch;
  float* FYa = wsf + (size_t)3 * nch;
  float* FYe = wsf + (size_t)4 * nch;
  const int grid = nch / 256;

  k_pass<FS, 0><<<grid, 256, 0, stream>>>(x, tauA, tauD, nu, dbreg, nullptr, nullptr, nullptr, A, B);
  k_scan<FS, 0><<<nseries, 256, 0, stream>>>(A, B, FYd, tauA, tauD, nu, dbreg);
  k_pass<FS, 1><<<grid, 256, 0, stream>>>(x, tauA, tauD, nu, dbreg, FYd, nullptr, nullptr, A, B);
  k_scan<FS, 1><<<nseries, 256, 0, stream>>>(A, B, FYa, tauA, tauD, nu, dbreg);
  k_pass<FS, 2><<<grid, 256, 0, stream>>>(x, tauA, tauD, nu, dbreg, FYd, FYa, nullptr, A, B);
  k_scan<FS, 0><<<nseries, 256, 0, stream>>>(A, B, FYe, tauA, tauD, nu, dbreg);
  k_pass<FS, 3><<<grid, 256, 0, stream>>>(x, tauA, tauD, nu, dbreg, FYd, FYa, FYe, out, nullptr);
}

extern "C" void kernel_launch(void* const* d_in, const int* in_sizes, int n_in,
                              void* d_out, int out_size, void* d_ws, size_t ws_size,
                              hipStream_t stream) {
  const float* x     = (const float*)d_in[0];
  const float* tauA  = (const float*)d_in[1];
  const float* tauD  = (const float*)d_in[2];
  const float* nu    = (const float*)d_in[3];
  const float* dbreg = (const float*)d_in[4];
  float* out = (float*)d_out;
  float* wsf = (float*)d_ws;
  const int nseries = in_sizes[0] / kT;       // 256

  constexpr size_t LDSZ = (size_t)(2 * BUF_F + 5 * NC) * sizeof(float); // 134212 B

  static int fusedOK = -1;                    // one-time host-side probe
  if (fusedOK < 0) {
    hipFuncSetAttribute(reinterpret_cast<const void*>(&k_one),
                        hipFuncAttributeMaxDynamicSharedMemorySize, (int)LDSZ);
    (void)hipGetLastError();                  // clear any error state
    fusedOK = 1;
  }

  if (fusedOK == 1) {
    k_one<<<nseries, 256, LDSZ, stream>>>(x, tauA, tauD, nu, dbreg, out);
    if (hipGetLastError() == hipSuccess) return;
    fusedOK = 0;                              // LDS rejected -> pipeline forever
  }

  auto fits = [&](int FS) {
    return (size_t)5 * nseries * (kT / FS) * sizeof(float) <= ws_size;
  };
  if      (fits(40))  run_pipeline<40 >(x, tauA, tauD, nu, dbreg, out, wsf, nseries, stream);
  else if (fits(56))  run_pipeline<56 >(x, tauA, tauD, nu, dbreg, out, wsf, nseries, stream);
  else if (fits(72))  run_pipeline<72 >(x, tauA, tauD, nu, dbreg, out, wsf, nseries, stream);
  else                run_pipeline<120>(x, tauA, tauD, nu, dbreg, out, wsf, nseries, stream);
}